// Round 5
// baseline (269.559 us; speedup 1.0000x reference)
//
#include <hip/hip_runtime.h>
#include <hip/hip_bf16.h>

typedef __attribute__((ext_vector_type(8))) short s16x8;
typedef __attribute__((ext_vector_type(4))) float f32x4;

__device__ __forceinline__ unsigned short f2b(float x) {
  unsigned int u = __float_as_uint(x);
  u = (u + 0x7fffu + ((u >> 16) & 1u)) >> 16;
  return (unsigned short)u;
}

__device__ __forceinline__ float b2f(unsigned short u) {
  return __uint_as_float((unsigned int)u << 16);
}

// packed f32x2 -> bf16x2 (RNE), lo = a, hi = b
__device__ __forceinline__ unsigned int cvtpk(float a, float b) {
  unsigned int r;
  asm("v_cvt_pk_bf16_f32 %0, %1, %2" : "=v"(r) : "v"(a), "v"(b));
  return r;
}

#if __has_builtin(__builtin_amdgcn_exp2f)
__device__ __forceinline__ float fexp2(float x) { return __builtin_amdgcn_exp2f(x); }
#else
__device__ __forceinline__ float fexp2(float x) { return exp2f(x); }
#endif

// async 16B/lane global->LDS (lane i lands at lds + i*16)
__device__ __forceinline__ void gl2lds16(const unsigned short* g, unsigned short* lds) {
  __builtin_amdgcn_global_load_lds(
      (const __attribute__((address_space(1))) unsigned int*)g,
      (__attribute__((address_space(3))) unsigned int*)lds, 16, 0, 0);
}

#define QSCALE 0.18033688011f  /* 0.125 * log2(e): scores land in log2 domain */

// ---------------------------------------------------------------- fused cast fp32 -> bf16
__global__ __launch_bounds__(256) void cast_all(
    const float* __restrict__ x,  const float* __restrict__ Wq,
    const float* __restrict__ Wk, const float* __restrict__ Wv,
    const float* __restrict__ Wo, unsigned short* __restrict__ dst) {
  int i = blockIdx.x * 256 + threadIdx.x;
  const float* src;
  int off;
  if (i < 1048576) { src = x; off = i; }
  else {
    int j = i - 1048576;
    int seg = j >> 18;
    off = j & 262143;
    src = (seg == 0) ? Wq : (seg == 1) ? Wk : (seg == 2) ? Wv : Wo;
  }
  const float4 v = ((const float4*)src)[off];
  uint2 o;
  o.x = cvtpk(v.x, v.y);
  o.y = cvtpk(v.z, v.w);
  ((uint2*)dst)[i] = o;
}

#define KDIM 1024

// ---------------------------------------------------------------- QKV GEMM + fused RoPE
// R5: main loop was LDS-read-pipe-bound (96 ds_read_b128 per CU-generation vs
// ~240cyc MFMA). B (weights) now loaded global->reg with 1-iter prefetch (bfn);
// Bs eliminated (LDS 32KB->16KB, ds_read traffic halved). A stays in LDS
// (A-direct would double L2 traffic). launch_bounds (256,3): +32 regs for
// bfr/bfn would spill at (256,4)'s 128-reg budget (R3 lesson).
// Epilogue: RoPE in regs (native __sincosf; do NOT table it: R1 regression),
// per-wave LDS transpose for full 128B stores (R2). Q pre-scaled 0.125*log2e.
__global__ __launch_bounds__(256, 3) void gemm_qkv(
    const unsigned short* __restrict__ A,
    const unsigned short* __restrict__ Bt,
    const int* __restrict__ tok,
    unsigned short* __restrict__ Qo,
    unsigned short* __restrict__ Ko,
    unsigned short* __restrict__ Vt) {
  __shared__ unsigned short As[2][128 * 32];
  const int tid = threadIdx.x;
  const int bid = blockIdx.x;          // 768 blocks
  const int xcd = bid & 7;
  const int loc = bid >> 3;            // 0..95
  const int m0 = (loc / 3) * 128;
  const int n0 = (xcd * 3 + loc % 3) * 128;
  const int w = tid >> 6, lane = tid & 63;
  const int ln = lane & 15, quad = lane >> 4;
  const int wm = (w >> 1) * 64, wn = (w & 1) * 64;

  const int rr = lane >> 2;
  const int gsw = ((lane & 3) ^ ((rr ^ (rr >> 2)) & 3)) * 8;
  const int sr = (ln ^ (ln >> 2)) & 3;   // read-side swizzle

  const f32x4 zero = {0.f, 0.f, 0.f, 0.f};
  f32x4 acc[4][4];
#pragma unroll
  for (int i = 0; i < 4; ++i)
#pragma unroll
    for (int j = 0; j < 4; ++j) acc[i][j] = zero;

#define QKV_STAGE(kb, p)                                                              \
  do {                                                                                \
    int col = (kb) * 32 + gsw;                                                        \
    gl2lds16(A  + (size_t)(m0 + w * 32 + rr) * KDIM + col,      &As[p][(w * 32) * 32]);      \
    gl2lds16(A  + (size_t)(m0 + w * 32 + 16 + rr) * KDIM + col, &As[p][(w * 32 + 16) * 32]); \
  } while (0)

  // B fragments: direct global->reg (clean 16B/lane, 64B sectors, L2-hot slice)
  const unsigned short* Bp = Bt + (size_t)(n0 + wn + ln) * KDIM + quad * 8;
  s16x8 bfr[4], bfn[4];
#pragma unroll
  for (int j = 0; j < 4; ++j)
    bfr[j] = *(const s16x8*)(Bp + (size_t)j * 16 * KDIM);

  QKV_STAGE(0, 0);
  for (int kb = 0; kb < 32; ++kb) {
    const int p = kb & 1;
    __syncthreads();
    if (kb < 31) {
      QKV_STAGE(kb + 1, p ^ 1);
#pragma unroll
      for (int j = 0; j < 4; ++j)
        bfn[j] = *(const s16x8*)(Bp + (size_t)j * 16 * KDIM + (kb + 1) * 32);
    }
    s16x8 af[4];
#pragma unroll
    for (int i = 0; i < 4; ++i)
      af[i] = *(const s16x8*)(&As[p][(wm + i * 16 + ln) * 32 + ((quad ^ sr) * 8)]);
#pragma unroll
    for (int i = 0; i < 4; ++i)
#pragma unroll
      for (int j = 0; j < 4; ++j)
        acc[i][j] = __builtin_amdgcn_mfma_f32_16x16x32_bf16(af[i], bfr[j], acc[i][j], 0, 0, 0);
    if (kb < 31) {
#pragma unroll
      for (int j = 0; j < 4; ++j) bfr[j] = bfn[j];
    }
  }
#undef QKV_STAGE

  __syncthreads();                      // all waves done reading As (epilogue reuses As)
  const bool isV = (n0 >= 2048);        // block-uniform (tiles fully Q, K, or V)
  if (!isV) {
    // Q/K: RoPE in regs, LDS transpose (16s x 64d per i-chunk), 128B stores.
    const float qs = (n0 + wn < 1024) ? QSCALE : 1.0f;
    const int gnb = n0 + wn;            // 64-aligned: one full head per wave
    const int h = (gnb & 1023) >> 6;    // uniform per wave
    unsigned short* dst = (gnb < 1024) ? Qo : Ko;
    unsigned short* T = &As[0][0] + w * 1088;   // per-wave 16 x 68 scratch
    float invj[4];
#pragma unroll
    for (int j = 0; j < 4; ++j)
      invj[j] = __expf(-0.2878231366f * (float)((j * 16 + ln) >> 1));
#pragma unroll
    for (int i = 0; i < 4; ++i) {
      const int mb = m0 + wm + i * 16;  // 16-row chunk, same b for all rows
      const int b = mb >> 11;
      const int sb = mb & 2047;
#pragma unroll
      for (int j = 0; j < 4; ++j) {
        const int dd = j * 16 + ln;
#pragma unroll
        for (int r = 0; r < 4; ++r) {
          float val = acc[i][j][r];
          float part = __shfl_xor(val, 1, 64);
          int s = sb + quad * 4 + r;
          float ang = (float)s * invj[j];   // positions are arange
          float sn, cs;
          __sincosf(ang, &sn, &cs);
          float x0 = (dd & 1) ? part : val;
          float x1 = (dd & 1) ? val : part;
          float y = (dd & 1) ? (x0 * sn + x1 * cs) : (x0 * cs - x1 * sn);
          T[(quad * 4 + r) * 68 + dd] = f2b(y * qs);
        }
      }
      __builtin_amdgcn_wave_barrier();    // DS in-order per wave
      const size_t obase = ((size_t)(b * 16 + h) * 2048 + sb) * 64;
#pragma unroll
      for (int ss = 0; ss < 16; ++ss)
        dst[obase + (size_t)ss * 64 + lane] = T[ss * 68 + lane];
      __builtin_amdgcn_wave_barrier();    // reads done before next i overwrite
    }
  } else {
    // V: transpose 16d x 64s tiles via LDS scratch (reuse As), coalesced stores
    unsigned short* T = &As[0][0] + w * 1120; // per-wave 16 x 64, stride 70
    const int b = m0 >> 11;
    const int hrow = ((n0 - 2048) + wn) >> 6; // head (uniform per wave)
    const int s0 = (m0 & 2047) + wm;
    const size_t vbase = (size_t)(b * 16 + hrow) * 64;
#pragma unroll
    for (int j = 0; j < 4; ++j) {
#pragma unroll
      for (int i = 0; i < 4; ++i)
#pragma unroll
        for (int r = 0; r < 4; ++r)
          T[ln * 70 + i * 16 + quad * 4 + r] = f2b(acc[i][j][r]);
      __builtin_amdgcn_wave_barrier();        // DS in-order per wave
#pragma unroll
      for (int dd = 0; dd < 16; ++dd)
        Vt[(vbase + j * 16 + dd) * 2048 + s0 + lane] = T[dd * 70 + lane];
      __builtin_amdgcn_wave_barrier();        // reads done before next j overwrite
    }
  }
}

// ---------------------------------------------------------------- split-K flash attention (dbuf LDS staging)
// R5: va (V fragments) hoisted out of the u-loop — was read twice per tile
// (8 ds_read_b128 per u-half); now once (-20% LDS traffic). rs cross-lane
// reduction deferred: l_i kept as per-lane partial (al is row-uniform), one
// butterfly after the k-loop instead of 2 shfl per u-half per tile.
// Keep (256,3): R3's (256,4) spilled. Pt XOR-swizzled (R3), LDS 40960.
__global__ __launch_bounds__(256, 3) void attn_partial(
    const unsigned short* __restrict__ Q,
    const unsigned short* __restrict__ K,
    const unsigned short* __restrict__ Vt,
    unsigned short* __restrict__ Opart,
    float2* __restrict__ ML) {
  __shared__ unsigned short Ks[2][64 * 64];
  __shared__ unsigned short Vs[2][64 * 64];
  __shared__ unsigned short Pt[4][16 * 64];   // per-wave 2048 B, XOR-swizzled

  const int bid = blockIdx.x;          // 1280 blocks
  const int xcd = bid & 7;
  const int loc = bid >> 3;            // 0..159
  const int bh = xcd * 4 + (loc & 3);
  const int widx = loc >> 2;           // 0..39, heavy-first
  int c, qh;
  if (widx < 28) {
    if (widx < 13)      { c = 0; qh = 3 + widx; }
    else if (widx < 22) { c = 1; qh = 7 + (widx - 13); }
    else if (widx < 27) { c = 2; qh = 11 + (widx - 22); }
    else                { c = 3; qh = 15; }
  } else {
    int s = widx - 28;
    int wt = s >> 2;
    c = s & 3;
    qh = 4 * c + 2 - wt;
  }
  const int kbeg = c * 512;
  const int khi = min(kbeg + 512, qh * 128 + 128);
  const int nit = (khi - kbeg) >> 6;   // 1..8, uniform per block

  const int tid = threadIdx.x;
  const int w = tid >> 6, lane = tid & 63;
  const int ln = lane & 15, quad = lane >> 4;
  const int qb = qh * 128 + w * 32;

  const unsigned short* Qb = Q + (size_t)bh * 2048 * 64;
  const unsigned short* Kb = K + (size_t)bh * 2048 * 64;
  const unsigned short* Vb = Vt + (size_t)bh * 64 * 2048;

  const int srow = w * 16 + (lane >> 3);
  const int sg = (lane & 7) ^ (srow & 7);

#define ATTN_STAGE(k0, p)                                                            \
  do {                                                                               \
    gl2lds16(Kb + (size_t)((k0) + srow) * 64 + sg * 8,       &Ks[p][(w * 16) * 64]);      \
    gl2lds16(Kb + (size_t)((k0) + srow + 8) * 64 + sg * 8,   &Ks[p][(w * 16 + 8) * 64]);  \
    gl2lds16(Vb + (size_t)srow * 2048 + (k0) + sg * 8,       &Vs[p][(w * 16) * 64]);      \
    gl2lds16(Vb + (size_t)(srow + 8) * 2048 + (k0) + sg * 8, &Vs[p][(w * 16 + 8) * 64]);  \
  } while (0)

  s16x8 bq[2][2];
#pragma unroll
  for (int u = 0; u < 2; ++u)
#pragma unroll
    for (int hh = 0; hh < 2; ++hh)
      bq[u][hh] = *(const s16x8*)(&Qb[(size_t)(qb + u * 16 + ln) * 64 + hh * 32 + quad * 8]);

  const f32x4 zero = {0.f, 0.f, 0.f, 0.f};
  f32x4 o[2][4];
#pragma unroll
  for (int u = 0; u < 2; ++u)
#pragma unroll
    for (int j = 0; j < 4; ++j) o[u][j] = zero;
  float m_i[2] = {-3e38f, -3e38f};
  float l_i[2] = {0.f, 0.f};           // per-lane partials until final butterfly

  const int rdsw = ((ln & 7) * 8);
  unsigned char* ptb = (unsigned char*)&Pt[w][0];
  const int pswz = (ln & 7) << 4;      // XOR swizzle for stride-64 rows

  ATTN_STAGE(kbeg, 0);
  for (int it = 0; it < nit; ++it) {
    const int p = it & 1;
    const int k0 = kbeg + it * 64;
    __syncthreads();                         // buf p staged; buf p^1 free
    if (it + 1 < nit) ATTN_STAGE(k0 + 64, p ^ 1);

    if (k0 <= qb + 31) {                     // wave-tile not fully above diagonal
      s16x8 ka[4][2];
#pragma unroll
      for (int t = 0; t < 4; ++t)
#pragma unroll
        for (int hh = 0; hh < 2; ++hh)
          ka[t][hh] = *(const s16x8*)(&Ks[p][(t * 16 + ln) * 64 + (((hh * 4 + quad) * 8) ^ rdsw)]);
      s16x8 va[2][4];                        // hoisted: shared by both u-halves
#pragma unroll
      for (int hh = 0; hh < 2; ++hh)
#pragma unroll
        for (int j = 0; j < 4; ++j)
          va[hh][j] = *(const s16x8*)(&Vs[p][(j * 16 + ln) * 64 + (((hh * 4 + quad) * 8) ^ rdsw)]);

#pragma unroll
      for (int u = 0; u < 2; ++u) {
        const int qlo = qb + u * 16;
        if (k0 > qlo + 15) continue;         // this u-half fully masked
        f32x4 st[4];
#pragma unroll
        for (int t = 0; t < 4; ++t) {
          f32x4 s = __builtin_amdgcn_mfma_f32_16x16x32_bf16(ka[t][0], bq[u][0], zero, 0, 0, 0);
          st[t] = __builtin_amdgcn_mfma_f32_16x16x32_bf16(ka[t][1], bq[u][1], s, 0, 0, 0);
        }
        float lm = -3e38f;
        if (k0 + 63 > qlo) {
          // diagonal tile: apply causal mask
          const int q = qlo + ln;
#pragma unroll
          for (int t = 0; t < 4; ++t)
#pragma unroll
            for (int r = 0; r < 4; ++r) {
              int kk = k0 + t * 16 + quad * 4 + r;
              float v = st[t][r];
              v = (kk > q) ? -3e38f : v;
              st[t][r] = v;
              lm = fmaxf(lm, v);
            }
        } else {
          // interior tile: no masking needed
#pragma unroll
          for (int t = 0; t < 4; ++t)
#pragma unroll
            for (int r = 0; r < 4; ++r) lm = fmaxf(lm, st[t][r]);
        }
        lm = fmaxf(lm, __shfl_xor(lm, 16, 64));
        lm = fmaxf(lm, __shfl_xor(lm, 32, 64));

        float rs = 0.f;
        if (__all(lm <= m_i[u])) {
          // running max unchanged: al == 1 exactly, skip rescale
          const float mn = m_i[u];
#pragma unroll
          for (int t = 0; t < 4; ++t)
#pragma unroll
            for (int r = 0; r < 4; ++r) {
              float pv = fexp2(st[t][r] - mn);
              st[t][r] = pv;
              rs += pv;
            }
          l_i[u] += rs;                      // per-lane partial
        } else {
          const float mn = fmaxf(m_i[u], lm);
          const float al = fexp2(m_i[u] - mn);  // row-uniform (lm reduced over quad)
#pragma unroll
          for (int t = 0; t < 4; ++t)
#pragma unroll
            for (int r = 0; r < 4; ++r) {
              float pv = fexp2(st[t][r] - mn);
              st[t][r] = pv;
              rs += pv;
            }
          m_i[u] = mn;
          l_i[u] = l_i[u] * al + rs;         // per-lane partial
#pragma unroll
          for (int j = 0; j < 4; ++j) o[u][j] *= al;
        }

#pragma unroll
        for (int t = 0; t < 4; ++t) {
          uint2 pv;
          pv.x = cvtpk(st[t][0], st[t][1]);
          pv.y = cvtpk(st[t][2], st[t][3]);
          *(uint2*)(ptb + ln * 128 + ((t * 32 + quad * 8) ^ pswz)) = pv;
        }
        __builtin_amdgcn_wave_barrier();
#pragma unroll
        for (int hh = 0; hh < 2; ++hh) {
          s16x8 pb = *(const s16x8*)(ptb + ln * 128 + ((hh * 64 + quad * 16) ^ pswz));
#pragma unroll
          for (int j = 0; j < 4; ++j)
            o[u][j] = __builtin_amdgcn_mfma_f32_16x16x32_bf16(va[hh][j], pb, o[u][j], 0, 0, 0);
        }
        __builtin_amdgcn_wave_barrier();
      }
    }
  }
#undef ATTN_STAGE

  // final cross-lane reduce of the deferred l partials (butterfly over quad)
#pragma unroll
  for (int u = 0; u < 2; ++u) {
    l_i[u] += __shfl_xor(l_i[u], 16, 64);
    l_i[u] += __shfl_xor(l_i[u], 32, 64);
  }

#pragma unroll
  for (int u = 0; u < 2; ++u) {
    int s = qb + u * 16 + ln;
    size_t row = ((size_t)bh * 4 + c) * 2048 + s;
    if (quad == 0) ML[row] = make_float2(m_i[u], l_i[u]);
    size_t base = row * 64;
#pragma unroll
    for (int j = 0; j < 4; ++j) {
      uint2 o4;
      o4.x = cvtpk(o[u][j][0], o[u][j][1]);
      o4.y = cvtpk(o[u][j][2], o[u][j][3]);
      *(uint2*)(&Opart[base + j * 16 + quad * 4]) = o4;
    }
  }
}

// ---------------------------------------------------------------- merge partials -> Ab
__global__ __launch_bounds__(256) void attn_merge(
    const unsigned short* __restrict__ Opart,
    const float2* __restrict__ ML,
    unsigned short* __restrict__ Ao) {
  int idx = blockIdx.x * 256 + threadIdx.x;
  int d0 = (idx & 7) * 8;
  int q  = (idx >> 3) & 2047;
  int bh = idx >> 14;
  int nc = (q >> 9) + 1;

  float m_c[4], l_c[4];
  float M = -3e38f;
  for (int c = 0; c < nc; ++c) {
    float2 ml = ML[((size_t)bh * 4 + c) * 2048 + q];
    m_c[c] = ml.x; l_c[c] = ml.y;
    M = fmaxf(M, ml.x);
  }
  float acc[8] = {0, 0, 0, 0, 0, 0, 0, 0};
  float L = 0.f;
  for (int c = 0; c < nc; ++c) {
    float wc = fexp2(m_c[c] - M);      // log2-domain running max
    L += wc * l_c[c];
    const ushort4* p = (const ushort4*)(Opart + (((size_t)bh * 4 + c) * 2048 + q) * 64 + d0);
    ushort4 a = p[0], bvec = p[1];
    acc[0] += wc * b2f(a.x); acc[1] += wc * b2f(a.y);
    acc[2] += wc * b2f(a.z); acc[3] += wc * b2f(a.w);
    acc[4] += wc * b2f(bvec.x); acc[5] += wc * b2f(bvec.y);
    acc[6] += wc * b2f(bvec.z); acc[7] += wc * b2f(bvec.w);
  }
  float invL = 1.0f / L;
  int b = bh >> 4, h = bh & 15;
  unsigned short* dst = Ao + ((size_t)b * 2048 + q) * 1024 + h * 64 + d0;
  uint2 o0, o1;
  o0.x = cvtpk(acc[0] * invL, acc[1] * invL);
  o0.y = cvtpk(acc[2] * invL, acc[3] * invL);
  o1.x = cvtpk(acc[4] * invL, acc[5] * invL);
  o1.y = cvtpk(acc[6] * invL, acc[7] * invL);
  ((uint2*)dst)[0] = o0;
  ((uint2*)dst)[1] = o1;
}

// ---------------------------------------------------------------- output projection GEMM
// single-buffered BK=64, (256,3) residency cap.
__global__ __launch_bounds__(256, 3) void gemm_out(
    const unsigned short* __restrict__ A,
    const unsigned short* __restrict__ Bt,
    float* __restrict__ out) {
  __shared__ unsigned short As[128 * 64];
  __shared__ unsigned short Bs[128 * 64];
  const int tid = threadIdx.x;
  const int bid = blockIdx.x;          // 256 blocks
  const int m0 = (bid >> 3) * 128;
  const int n0 = (bid & 7) * 128;
  const int w = tid >> 6, lane = tid & 63;
  const int ln = lane & 15, quad = lane >> 4;
  const int wm = (w >> 1) * 64, wn = (w & 1) * 64;

  const int srow = w * 32 + (lane >> 3);
  const int sg = (lane & 7) ^ (lane >> 3);
  const int rs = ln & 7;

  const f32x4 zero = {0.f, 0.f, 0.f, 0.f};
  f32x4 acc[4][4];
#pragma unroll
  for (int i = 0; i < 4; ++i)
#pragma unroll
    for (int j = 0; j < 4; ++j) acc[i][j] = zero;

  for (int kb = 0; kb < KDIM / 64; ++kb) {
    __syncthreads();
#pragma unroll
    for (int t = 0; t < 4; ++t) {
      gl2lds16(A  + (size_t)(m0 + srow + t * 8) * KDIM + kb * 64 + sg * 8, &As[(w * 32 + t * 8) * 64]);
      gl2lds16(Bt + (size_t)(n0 + srow + t * 8) * KDIM + kb * 64 + sg * 8, &Bs[(w * 32 + t * 8) * 64]);
    }
    __syncthreads();
#pragma unroll
    for (int ks = 0; ks < 2; ++ks) {
      s16x8 af[4], bfr[4];
#pragma unroll
      for (int i = 0; i < 4; ++i)
        af[i] = *(const s16x8*)(&As[(wm + i * 16 + ln) * 64 + (((ks * 4 + quad) ^ rs) * 8)]);
#pragma unroll
      for (int j = 0; j < 4; ++j)
        bfr[j] = *(const s16x8*)(&Bs[(wn + j * 16 + ln) * 64 + (((ks * 4 + quad) ^ rs) * 8)]);
#pragma unroll
      for (int i = 0; i < 4; ++i)
#pragma unroll
        for (int j = 0; j < 4; ++j)
          acc[i][j] = __builtin_amdgcn_mfma_f32_16x16x32_bf16(af[i], bfr[j], acc[i][j], 0, 0, 0);
    }
  }
#pragma unroll
  for (int i = 0; i < 4; ++i) {
    int gmb = m0 + wm + i * 16 + quad * 4;
#pragma unroll
    for (int j = 0; j < 4; ++j) {
      int gn = n0 + wn + j * 16 + ln;
#pragma unroll
      for (int r = 0; r < 4; ++r)
        out[(size_t)(gmb + r) * 1024 + gn] = acc[i][j][r];
    }
  }
}

// ---------------------------------------------------------------- launch
extern "C" void kernel_launch(void* const* d_in, const int* in_sizes, int n_in,
                              void* d_out, int out_size, void* d_ws, size_t ws_size,
                              hipStream_t stream) {
  const float* x  = (const float*)d_in[0];
  const float* Wq = (const float*)d_in[1];
  const float* Wk = (const float*)d_in[2];
  const float* Wv = (const float*)d_in[3];
  const float* Wo = (const float*)d_in[4];
  const int* tok  = (const int*)d_in[5];
  float* out = (float*)d_out;

  char* ws = (char*)d_ws;
  unsigned short* xb    = (unsigned short*)(ws);                  // 8 MB
  unsigned short* Wcat  = (unsigned short*)(ws + (8ull  << 20));  // 6 MB
  unsigned short* Wob   = (unsigned short*)(ws + (14ull << 20));  // 2 MB
  unsigned short* Qb    = (unsigned short*)(ws + (16ull << 20));  // 8 MB
  unsigned short* Kb    = (unsigned short*)(ws + (24ull << 20));  // 8 MB
  unsigned short* Vtb   = (unsigned short*)(ws + (32ull << 20));  // 8 MB
  unsigned short* Ab    = (unsigned short*)(ws + (40ull << 20));  // 8 MB
  unsigned short* Opart = (unsigned short*)(ws + (48ull << 20));  // 32 MB
  float2*         ML    = (float2*)        (ws + (80ull << 20));  // 2 MB

  cast_all<<<dim3(8192), dim3(256), 0, stream>>>(x, Wq, Wk, Wv, Wo, xb);
  gemm_qkv<<<dim3(768), dim3(256), 0, stream>>>(xb, Wcat, tok, Qb, Kb, Vtb);
  attn_partial<<<dim3(1280), dim3(256), 0, stream>>>(Qb, Kb, Vtb, Opart, ML);
  attn_merge<<<dim3(2048), dim3(256), 0, stream>>>(Opart, ML, Ab);
  gemm_out<<<dim3(256), dim3(256), 0, stream>>>(Ab, Wob, out);
}

// Round 6
// 192.952 us; speedup vs baseline: 1.3970x; 1.3970x over previous
//
#include <hip/hip_runtime.h>
#include <hip/hip_bf16.h>

typedef __attribute__((ext_vector_type(8))) short s16x8;
typedef __attribute__((ext_vector_type(4))) float f32x4;

__device__ __forceinline__ unsigned short f2b(float x) {
  unsigned int u = __float_as_uint(x);
  u = (u + 0x7fffu + ((u >> 16) & 1u)) >> 16;
  return (unsigned short)u;
}

__device__ __forceinline__ float b2f(unsigned short u) {
  return __uint_as_float((unsigned int)u << 16);
}

// packed f32x2 -> bf16x2 (RNE), lo = a, hi = b
__device__ __forceinline__ unsigned int cvtpk(float a, float b) {
  unsigned int r;
  asm("v_cvt_pk_bf16_f32 %0, %1, %2" : "=v"(r) : "v"(a), "v"(b));
  return r;
}

#if __has_builtin(__builtin_amdgcn_exp2f)
__device__ __forceinline__ float fexp2(float x) { return __builtin_amdgcn_exp2f(x); }
#else
__device__ __forceinline__ float fexp2(float x) { return exp2f(x); }
#endif

// async 16B/lane global->LDS (lane i lands at lds + i*16)
__device__ __forceinline__ void gl2lds16(const unsigned short* g, unsigned short* lds) {
  __builtin_amdgcn_global_load_lds(
      (const __attribute__((address_space(1))) unsigned int*)g,
      (__attribute__((address_space(3))) unsigned int*)lds, 16, 0, 0);
}

#define QSCALE 0.18033688011f  /* 0.125 * log2(e): scores land in log2 domain */

// ---------------------------------------------------------------- fused cast fp32 -> bf16
__global__ __launch_bounds__(256) void cast_all(
    const float* __restrict__ x,  const float* __restrict__ Wq,
    const float* __restrict__ Wk, const float* __restrict__ Wv,
    const float* __restrict__ Wo, unsigned short* __restrict__ dst) {
  int i = blockIdx.x * 256 + threadIdx.x;
  const float* src;
  int off;
  if (i < 1048576) { src = x; off = i; }
  else {
    int j = i - 1048576;
    int seg = j >> 18;
    off = j & 262143;
    src = (seg == 0) ? Wq : (seg == 1) ? Wk : (seg == 2) ? Wv : Wo;
  }
  const float4 v = ((const float4*)src)[off];
  uint2 o;
  o.x = cvtpk(v.x, v.y);
  o.y = cvtpk(v.z, v.w);
  ((uint2*)dst)[i] = o;
}

#define KDIM 1024

// ---------------------------------------------------------------- QKV GEMM + fused RoPE
// R6: reverted to R4's Bs-in-LDS version. R5's B-direct-to-reg regressed ~20us:
// bfr/bfn loads share the vmcnt counter with global_load_lds, so waiting on B
// fragments also drained the next tile's staging -> dbuf overlap destroyed.
// Epilogue: RoPE in regs (native __sincosf; do NOT table: R1), per-wave LDS
// transpose for full 128B stores (R2). Q pre-scaled 0.125*log2e.
__global__ __launch_bounds__(256, 4) void gemm_qkv(
    const unsigned short* __restrict__ A,
    const unsigned short* __restrict__ Bt,
    const int* __restrict__ tok,
    unsigned short* __restrict__ Qo,
    unsigned short* __restrict__ Ko,
    unsigned short* __restrict__ Vt) {
  __shared__ unsigned short As[2][128 * 32];
  __shared__ unsigned short Bs[2][128 * 32];
  const int tid = threadIdx.x;
  const int bid = blockIdx.x;          // 768 blocks
  const int xcd = bid & 7;
  const int loc = bid >> 3;            // 0..95
  const int m0 = (loc / 3) * 128;
  const int n0 = (xcd * 3 + loc % 3) * 128;
  const int w = tid >> 6, lane = tid & 63;
  const int ln = lane & 15, quad = lane >> 4;
  const int wm = (w >> 1) * 64, wn = (w & 1) * 64;

  const int rr = lane >> 2;
  const int gsw = ((lane & 3) ^ ((rr ^ (rr >> 2)) & 3)) * 8;
  const int sr = (ln ^ (ln >> 2)) & 3;   // read-side swizzle

  const f32x4 zero = {0.f, 0.f, 0.f, 0.f};
  f32x4 acc[4][4];
#pragma unroll
  for (int i = 0; i < 4; ++i)
#pragma unroll
    for (int j = 0; j < 4; ++j) acc[i][j] = zero;

#define QKV_STAGE(kb, p)                                                              \
  do {                                                                                \
    int col = (kb) * 32 + gsw;                                                        \
    gl2lds16(A  + (size_t)(m0 + w * 32 + rr) * KDIM + col,      &As[p][(w * 32) * 32]);      \
    gl2lds16(A  + (size_t)(m0 + w * 32 + 16 + rr) * KDIM + col, &As[p][(w * 32 + 16) * 32]); \
    gl2lds16(Bt + (size_t)(n0 + w * 32 + rr) * KDIM + col,      &Bs[p][(w * 32) * 32]);      \
    gl2lds16(Bt + (size_t)(n0 + w * 32 + 16 + rr) * KDIM + col, &Bs[p][(w * 32 + 16) * 32]); \
  } while (0)

  QKV_STAGE(0, 0);
  for (int kb = 0; kb < 32; ++kb) {
    const int p = kb & 1;
    __syncthreads();
    if (kb < 31) QKV_STAGE(kb + 1, p ^ 1);
    s16x8 af[4], bfr[4];
#pragma unroll
    for (int i = 0; i < 4; ++i)
      af[i] = *(const s16x8*)(&As[p][(wm + i * 16 + ln) * 32 + ((quad ^ sr) * 8)]);
#pragma unroll
    for (int j = 0; j < 4; ++j)
      bfr[j] = *(const s16x8*)(&Bs[p][(wn + j * 16 + ln) * 32 + ((quad ^ sr) * 8)]);
#pragma unroll
    for (int i = 0; i < 4; ++i)
#pragma unroll
      for (int j = 0; j < 4; ++j)
        acc[i][j] = __builtin_amdgcn_mfma_f32_16x16x32_bf16(af[i], bfr[j], acc[i][j], 0, 0, 0);
  }
#undef QKV_STAGE

  __syncthreads();                      // all waves done reading As/Bs (epilogue reuses As)
  const bool isV = (n0 >= 2048);        // block-uniform (tiles fully Q, K, or V)
  if (!isV) {
    // Q/K: RoPE in regs, LDS transpose (16s x 64d per i-chunk), 128B stores.
    const float qs = (n0 + wn < 1024) ? QSCALE : 1.0f;
    const int gnb = n0 + wn;            // 64-aligned: one full head per wave
    const int h = (gnb & 1023) >> 6;    // uniform per wave
    unsigned short* dst = (gnb < 1024) ? Qo : Ko;
    unsigned short* T = &As[0][0] + w * 1088;   // per-wave 16 x 68 scratch
    float invj[4];
#pragma unroll
    for (int j = 0; j < 4; ++j)
      invj[j] = __expf(-0.2878231366f * (float)((j * 16 + ln) >> 1));
#pragma unroll
    for (int i = 0; i < 4; ++i) {
      const int mb = m0 + wm + i * 16;  // 16-row chunk, same b for all rows
      const int b = mb >> 11;
      const int sb = mb & 2047;
#pragma unroll
      for (int j = 0; j < 4; ++j) {
        const int dd = j * 16 + ln;
#pragma unroll
        for (int r = 0; r < 4; ++r) {
          float val = acc[i][j][r];
          float part = __shfl_xor(val, 1, 64);
          int s = sb + quad * 4 + r;
          float ang = (float)s * invj[j];   // positions are arange
          float sn, cs;
          __sincosf(ang, &sn, &cs);
          float x0 = (dd & 1) ? part : val;
          float x1 = (dd & 1) ? val : part;
          float y = (dd & 1) ? (x0 * sn + x1 * cs) : (x0 * cs - x1 * sn);
          T[(quad * 4 + r) * 68 + dd] = f2b(y * qs);
        }
      }
      __builtin_amdgcn_wave_barrier();    // DS in-order per wave
      const size_t obase = ((size_t)(b * 16 + h) * 2048 + sb) * 64;
#pragma unroll
      for (int ss = 0; ss < 16; ++ss)
        dst[obase + (size_t)ss * 64 + lane] = T[ss * 68 + lane];
      __builtin_amdgcn_wave_barrier();    // reads done before next i overwrite
    }
  } else {
    // V: transpose 16d x 64s tiles via LDS scratch (reuse As), coalesced stores
    unsigned short* T = &As[0][0] + w * 1120; // per-wave 16 x 64, stride 70
    const int b = m0 >> 11;
    const int hrow = ((n0 - 2048) + wn) >> 6; // head (uniform per wave)
    const int s0 = (m0 & 2047) + wm;
    const size_t vbase = (size_t)(b * 16 + hrow) * 64;
#pragma unroll
    for (int j = 0; j < 4; ++j) {
#pragma unroll
      for (int i = 0; i < 4; ++i)
#pragma unroll
        for (int r = 0; r < 4; ++r)
          T[ln * 70 + i * 16 + quad * 4 + r] = f2b(acc[i][j][r]);
      __builtin_amdgcn_wave_barrier();        // DS in-order per wave
#pragma unroll
      for (int dd = 0; dd < 16; ++dd)
        Vt[(vbase + j * 16 + dd) * 2048 + s0 + lane] = T[dd * 70 + lane];
      __builtin_amdgcn_wave_barrier();        // reads done before next j overwrite
    }
  }
}

// ---------------------------------------------------------------- split-K flash attention
// R6 restructure: 8-wave (512-thread) blocks, 256 q-rows per block, KVBLK=64
// staging shared by all 8 waves. Per-wave LDS cost halves -> 48KB/block,
// 3 blocks/CU = 24 waves/CU (was 12) against a latency-bound profile
// (R4: MfmaUtil 15 / VALU 39 / HBM 12 / occ 22 — nothing saturated).
// K/V HBM staging traffic also halves. Tile body = R4 exactly (no va hoist —
// that spilled in R5) + zero-register deferred-l (butterfly once at end).
// launch_bounds (512,2): no allocator squeeze (R3 lesson).
__global__ __launch_bounds__(512, 2) void attn_partial(
    const unsigned short* __restrict__ Q,
    const unsigned short* __restrict__ K,
    const unsigned short* __restrict__ Vt,
    unsigned short* __restrict__ Opart,
    float2* __restrict__ ML) {
  __shared__ unsigned short Ks[2][64 * 64];
  __shared__ unsigned short Vs[2][64 * 64];
  __shared__ unsigned short Pt[8][16 * 64];   // per-wave 2048 B, XOR-swizzled

  const int bid = blockIdx.x;          // 640 blocks
  const int xcd = bid & 7;
  const int loc = bid >> 3;            // 0..79
  const int bh = xcd * 4 + (loc & 3);
  const int widx = loc >> 2;           // 0..19, heavy-first
  int c, qh2;
  if (widx < 16) {                     // 16 heavy blocks (nit=8)
    qh2 = (int)((0x7777666555443321ull >> (widx * 4)) & 15);
    c   = (int)((0x3210210210101000ull >> (widx * 4)) & 15);
  } else {                             // 4 light blocks (nit=4)
    qh2 = (widx - 16) * 2;
    c   = widx - 16;
  }
  const int kbeg = c * 512;
  const int khi = min(kbeg + 512, qh2 * 256 + 256);
  const int nit = (khi - kbeg) >> 6;   // 4 or 8, uniform per block

  const int tid = threadIdx.x;
  const int w = tid >> 6, lane = tid & 63;   // w = 0..7
  const int ln = lane & 15, quad = lane >> 4;
  const int qb = qh2 * 256 + w * 32;

  const unsigned short* Qb = Q + (size_t)bh * 2048 * 64;
  const unsigned short* Kb = K + (size_t)bh * 2048 * 64;
  const unsigned short* Vb = Vt + (size_t)bh * 64 * 2048;

  const int srow = w * 8 + (lane >> 3);      // 64 rows over 8 waves
  const int sg = (lane & 7) ^ (srow & 7);

#define ATTN_STAGE(k0, p)                                                      \
  do {                                                                         \
    gl2lds16(Kb + (size_t)((k0) + srow) * 64 + sg * 8, &Ks[p][(w * 8) * 64]);  \
    gl2lds16(Vb + (size_t)srow * 2048 + (k0) + sg * 8, &Vs[p][(w * 8) * 64]);  \
  } while (0)

  s16x8 bq[2][2];
#pragma unroll
  for (int u = 0; u < 2; ++u)
#pragma unroll
    for (int hh = 0; hh < 2; ++hh)
      bq[u][hh] = *(const s16x8*)(&Qb[(size_t)(qb + u * 16 + ln) * 64 + hh * 32 + quad * 8]);

  const f32x4 zero = {0.f, 0.f, 0.f, 0.f};
  f32x4 o[2][4];
#pragma unroll
  for (int u = 0; u < 2; ++u)
#pragma unroll
    for (int j = 0; j < 4; ++j) o[u][j] = zero;
  float m_i[2] = {-3e38f, -3e38f};
  float l_i[2] = {0.f, 0.f};           // per-lane partials until final butterfly

  const int rdsw = ((ln & 7) * 8);
  unsigned char* ptb = (unsigned char*)&Pt[w][0];
  const int pswz = (ln & 7) << 4;      // XOR swizzle for stride-64 rows

  ATTN_STAGE(kbeg, 0);
  for (int it = 0; it < nit; ++it) {
    const int p = it & 1;
    const int k0 = kbeg + it * 64;
    __syncthreads();                         // buf p staged; buf p^1 free
    if (it + 1 < nit) ATTN_STAGE(k0 + 64, p ^ 1);

    if (k0 <= qb + 31) {                     // wave-tile not fully above diagonal
      s16x8 ka[4][2];
#pragma unroll
      for (int t = 0; t < 4; ++t)
#pragma unroll
        for (int hh = 0; hh < 2; ++hh)
          ka[t][hh] = *(const s16x8*)(&Ks[p][(t * 16 + ln) * 64 + (((hh * 4 + quad) * 8) ^ rdsw)]);

#pragma unroll
      for (int u = 0; u < 2; ++u) {
        const int qlo = qb + u * 16;
        if (k0 > qlo + 15) continue;         // this u-half fully masked
        f32x4 st[4];
#pragma unroll
        for (int t = 0; t < 4; ++t) {
          f32x4 s = __builtin_amdgcn_mfma_f32_16x16x32_bf16(ka[t][0], bq[u][0], zero, 0, 0, 0);
          st[t] = __builtin_amdgcn_mfma_f32_16x16x32_bf16(ka[t][1], bq[u][1], s, 0, 0, 0);
        }
        float lm = -3e38f;
        if (k0 + 63 > qlo) {
          // diagonal tile: apply causal mask
          const int q = qlo + ln;
#pragma unroll
          for (int t = 0; t < 4; ++t)
#pragma unroll
            for (int r = 0; r < 4; ++r) {
              int kk = k0 + t * 16 + quad * 4 + r;
              float v = st[t][r];
              v = (kk > q) ? -3e38f : v;
              st[t][r] = v;
              lm = fmaxf(lm, v);
            }
        } else {
          // interior tile: no masking needed
#pragma unroll
          for (int t = 0; t < 4; ++t)
#pragma unroll
            for (int r = 0; r < 4; ++r) lm = fmaxf(lm, st[t][r]);
        }
        lm = fmaxf(lm, __shfl_xor(lm, 16, 64));
        lm = fmaxf(lm, __shfl_xor(lm, 32, 64));

        float rs = 0.f;
        if (__all(lm <= m_i[u])) {
          // running max unchanged: al == 1 exactly, skip rescale
          const float mn = m_i[u];
#pragma unroll
          for (int t = 0; t < 4; ++t)
#pragma unroll
            for (int r = 0; r < 4; ++r) {
              float pv = fexp2(st[t][r] - mn);
              st[t][r] = pv;
              rs += pv;
            }
          l_i[u] += rs;                      // per-lane partial
        } else {
          const float mn = fmaxf(m_i[u], lm);
          const float al = fexp2(m_i[u] - mn);  // row-uniform (lm reduced over quads)
#pragma unroll
          for (int t = 0; t < 4; ++t)
#pragma unroll
            for (int r = 0; r < 4; ++r) {
              float pv = fexp2(st[t][r] - mn);
              st[t][r] = pv;
              rs += pv;
            }
          m_i[u] = mn;
          l_i[u] = l_i[u] * al + rs;         // per-lane partial
#pragma unroll
          for (int j = 0; j < 4; ++j) o[u][j] *= al;
        }

#pragma unroll
        for (int t = 0; t < 4; ++t) {
          uint2 pv;
          pv.x = cvtpk(st[t][0], st[t][1]);
          pv.y = cvtpk(st[t][2], st[t][3]);
          *(uint2*)(ptb + ln * 128 + ((t * 32 + quad * 8) ^ pswz)) = pv;
        }
        __builtin_amdgcn_wave_barrier();
#pragma unroll
        for (int hh = 0; hh < 2; ++hh) {
          s16x8 pb = *(const s16x8*)(ptb + ln * 128 + ((hh * 64 + quad * 16) ^ pswz));
#pragma unroll
          for (int j = 0; j < 4; ++j) {
            s16x8 va = *(const s16x8*)(&Vs[p][(j * 16 + ln) * 64 + (((hh * 4 + quad) * 8) ^ rdsw)]);
            o[u][j] = __builtin_amdgcn_mfma_f32_16x16x32_bf16(va, pb, o[u][j], 0, 0, 0);
          }
        }
        __builtin_amdgcn_wave_barrier();
      }
    }
  }
#undef ATTN_STAGE

  // final cross-lane reduce of the deferred l partials
#pragma unroll
  for (int u = 0; u < 2; ++u) {
    l_i[u] += __shfl_xor(l_i[u], 16, 64);
    l_i[u] += __shfl_xor(l_i[u], 32, 64);
  }

#pragma unroll
  for (int u = 0; u < 2; ++u) {
    int s = qb + u * 16 + ln;
    size_t row = ((size_t)bh * 4 + c) * 2048 + s;
    if (quad == 0) ML[row] = make_float2(m_i[u], l_i[u]);
    size_t base = row * 64;
#pragma unroll
    for (int j = 0; j < 4; ++j) {
      uint2 o4;
      o4.x = cvtpk(o[u][j][0], o[u][j][1]);
      o4.y = cvtpk(o[u][j][2], o[u][j][3]);
      *(uint2*)(&Opart[base + j * 16 + quad * 4]) = o4;
    }
  }
}

// ---------------------------------------------------------------- merge partials -> Ab
__global__ __launch_bounds__(256) void attn_merge(
    const unsigned short* __restrict__ Opart,
    const float2* __restrict__ ML,
    unsigned short* __restrict__ Ao) {
  int idx = blockIdx.x * 256 + threadIdx.x;
  int d0 = (idx & 7) * 8;
  int q  = (idx >> 3) & 2047;
  int bh = idx >> 14;
  int nc = (q >> 9) + 1;

  float m_c[4], l_c[4];
  float M = -3e38f;
  for (int c = 0; c < nc; ++c) {
    float2 ml = ML[((size_t)bh * 4 + c) * 2048 + q];
    m_c[c] = ml.x; l_c[c] = ml.y;
    M = fmaxf(M, ml.x);
  }
  float acc[8] = {0, 0, 0, 0, 0, 0, 0, 0};
  float L = 0.f;
  for (int c = 0; c < nc; ++c) {
    float wc = fexp2(m_c[c] - M);      // log2-domain running max
    L += wc * l_c[c];
    const ushort4* p = (const ushort4*)(Opart + (((size_t)bh * 4 + c) * 2048 + q) * 64 + d0);
    ushort4 a = p[0], bvec = p[1];
    acc[0] += wc * b2f(a.x); acc[1] += wc * b2f(a.y);
    acc[2] += wc * b2f(a.z); acc[3] += wc * b2f(a.w);
    acc[4] += wc * b2f(bvec.x); acc[5] += wc * b2f(bvec.y);
    acc[6] += wc * b2f(bvec.z); acc[7] += wc * b2f(bvec.w);
  }
  float invL = 1.0f / L;
  int b = bh >> 4, h = bh & 15;
  unsigned short* dst = Ao + ((size_t)b * 2048 + q) * 1024 + h * 64 + d0;
  uint2 o0, o1;
  o0.x = cvtpk(acc[0] * invL, acc[1] * invL);
  o0.y = cvtpk(acc[2] * invL, acc[3] * invL);
  o1.x = cvtpk(acc[4] * invL, acc[5] * invL);
  o1.y = cvtpk(acc[6] * invL, acc[7] * invL);
  ((uint2*)dst)[0] = o0;
  ((uint2*)dst)[1] = o1;
}

// ---------------------------------------------------------------- output projection GEMM
// single-buffered BK=64, (256,3) residency cap.
__global__ __launch_bounds__(256, 3) void gemm_out(
    const unsigned short* __restrict__ A,
    const unsigned short* __restrict__ Bt,
    float* __restrict__ out) {
  __shared__ unsigned short As[128 * 64];
  __shared__ unsigned short Bs[128 * 64];
  const int tid = threadIdx.x;
  const int bid = blockIdx.x;          // 256 blocks
  const int m0 = (bid >> 3) * 128;
  const int n0 = (bid & 7) * 128;
  const int w = tid >> 6, lane = tid & 63;
  const int ln = lane & 15, quad = lane >> 4;
  const int wm = (w >> 1) * 64, wn = (w & 1) * 64;

  const int srow = w * 32 + (lane >> 3);
  const int sg = (lane & 7) ^ (lane >> 3);
  const int rs = ln & 7;

  const f32x4 zero = {0.f, 0.f, 0.f, 0.f};
  f32x4 acc[4][4];
#pragma unroll
  for (int i = 0; i < 4; ++i)
#pragma unroll
    for (int j = 0; j < 4; ++j) acc[i][j] = zero;

  for (int kb = 0; kb < KDIM / 64; ++kb) {
    __syncthreads();
#pragma unroll
    for (int t = 0; t < 4; ++t) {
      gl2lds16(A  + (size_t)(m0 + srow + t * 8) * KDIM + kb * 64 + sg * 8, &As[(w * 32 + t * 8) * 64]);
      gl2lds16(Bt + (size_t)(n0 + srow + t * 8) * KDIM + kb * 64 + sg * 8, &Bs[(w * 32 + t * 8) * 64]);
    }
    __syncthreads();
#pragma unroll
    for (int ks = 0; ks < 2; ++ks) {
      s16x8 af[4], bfr[4];
#pragma unroll
      for (int i = 0; i < 4; ++i)
        af[i] = *(const s16x8*)(&As[(wm + i * 16 + ln) * 64 + (((ks * 4 + quad) ^ rs) * 8)]);
#pragma unroll
      for (int j = 0; j < 4; ++j)
        bfr[j] = *(const s16x8*)(&Bs[(wn + j * 16 + ln) * 64 + (((ks * 4 + quad) ^ rs) * 8)]);
#pragma unroll
      for (int i = 0; i < 4; ++i)
#pragma unroll
        for (int j = 0; j < 4; ++j)
          acc[i][j] = __builtin_amdgcn_mfma_f32_16x16x32_bf16(af[i], bfr[j], acc[i][j], 0, 0, 0);
    }
  }
#pragma unroll
  for (int i = 0; i < 4; ++i) {
    int gmb = m0 + wm + i * 16 + quad * 4;
#pragma unroll
    for (int j = 0; j < 4; ++j) {
      int gn = n0 + wn + j * 16 + ln;
#pragma unroll
      for (int r = 0; r < 4; ++r)
        out[(size_t)(gmb + r) * 1024 + gn] = acc[i][j][r];
    }
  }
}

// ---------------------------------------------------------------- launch
extern "C" void kernel_launch(void* const* d_in, const int* in_sizes, int n_in,
                              void* d_out, int out_size, void* d_ws, size_t ws_size,
                              hipStream_t stream) {
  const float* x  = (const float*)d_in[0];
  const float* Wq = (const float*)d_in[1];
  const float* Wk = (const float*)d_in[2];
  const float* Wv = (const float*)d_in[3];
  const float* Wo = (const float*)d_in[4];
  const int* tok  = (const int*)d_in[5];
  float* out = (float*)d_out;

  char* ws = (char*)d_ws;
  unsigned short* xb    = (unsigned short*)(ws);                  // 8 MB
  unsigned short* Wcat  = (unsigned short*)(ws + (8ull  << 20));  // 6 MB
  unsigned short* Wob   = (unsigned short*)(ws + (14ull << 20));  // 2 MB
  unsigned short* Qb    = (unsigned short*)(ws + (16ull << 20));  // 8 MB
  unsigned short* Kb    = (unsigned short*)(ws + (24ull << 20));  // 8 MB
  unsigned short* Vtb   = (unsigned short*)(ws + (32ull << 20));  // 8 MB
  unsigned short* Ab    = (unsigned short*)(ws + (40ull << 20));  // 8 MB
  unsigned short* Opart = (unsigned short*)(ws + (48ull << 20));  // 32 MB
  float2*         ML    = (float2*)        (ws + (80ull << 20));  // 2 MB

  cast_all<<<dim3(8192), dim3(256), 0, stream>>>(x, Wq, Wk, Wv, Wo, xb);
  gemm_qkv<<<dim3(768), dim3(256), 0, stream>>>(xb, Wcat, tok, Qb, Kb, Vtb);
  attn_partial<<<dim3(640), dim3(512), 0, stream>>>(Qb, Kb, Vtb, Opart, ML);
  attn_merge<<<dim3(2048), dim3(256), 0, stream>>>(Opart, ML, Ab);
  gemm_out<<<dim3(256), dim3(256), 0, stream>>>(Ab, Wob, out);
}

// Round 7
// 186.761 us; speedup vs baseline: 1.4433x; 1.0331x over previous
//
#include <hip/hip_runtime.h>
#include <hip/hip_bf16.h>

typedef __attribute__((ext_vector_type(8))) short s16x8;
typedef __attribute__((ext_vector_type(4))) float f32x4;

__device__ __forceinline__ unsigned short f2b(float x) {
  unsigned int u = __float_as_uint(x);
  u = (u + 0x7fffu + ((u >> 16) & 1u)) >> 16;
  return (unsigned short)u;
}

__device__ __forceinline__ float b2f(unsigned short u) {
  return __uint_as_float((unsigned int)u << 16);
}

// packed f32x2 -> bf16x2 (RNE), lo = a, hi = b
__device__ __forceinline__ unsigned int cvtpk(float a, float b) {
  unsigned int r;
  asm("v_cvt_pk_bf16_f32 %0, %1, %2" : "=v"(r) : "v"(a), "v"(b));
  return r;
}

#if __has_builtin(__builtin_amdgcn_exp2f)
__device__ __forceinline__ float fexp2(float x) { return __builtin_amdgcn_exp2f(x); }
#else
__device__ __forceinline__ float fexp2(float x) { return exp2f(x); }
#endif

// async 16B/lane global->LDS (lane i lands at lds + i*16)
__device__ __forceinline__ void gl2lds16(const unsigned short* g, unsigned short* lds) {
  __builtin_amdgcn_global_load_lds(
      (const __attribute__((address_space(1))) unsigned int*)g,
      (__attribute__((address_space(3))) unsigned int*)lds, 16, 0, 0);
}

#define QSCALE 0.18033688011f  /* 0.125 * log2(e): scores land in log2 domain */

// ---------------------------------------------------------------- fused cast fp32 -> bf16
__global__ __launch_bounds__(256) void cast_all(
    const float* __restrict__ x,  const float* __restrict__ Wq,
    const float* __restrict__ Wk, const float* __restrict__ Wv,
    const float* __restrict__ Wo, unsigned short* __restrict__ dst) {
  int i = blockIdx.x * 256 + threadIdx.x;
  const float* src;
  int off;
  if (i < 1048576) { src = x; off = i; }
  else {
    int j = i - 1048576;
    int seg = j >> 18;
    off = j & 262143;
    src = (seg == 0) ? Wq : (seg == 1) ? Wk : (seg == 2) ? Wv : Wo;
  }
  const float4 v = ((const float4*)src)[off];
  uint2 o;
  o.x = cvtpk(v.x, v.y);
  o.y = cvtpk(v.z, v.w);
  ((uint2*)dst)[i] = o;
}

#define KDIM 1024

// ---------------------------------------------------------------- QKV GEMM + fused RoPE
// Bs-in-LDS dbuf BK=32 (R6 note: B-direct-to-reg regressed — B loads share
// vmcnt with global_load_lds, draining the staging pipeline; keep LDS path).
// Epilogue: RoPE in regs (native __sincosf; do NOT table: R1), per-wave LDS
// transpose for full 128B stores (R2). Q pre-scaled 0.125*log2e.
__global__ __launch_bounds__(256, 4) void gemm_qkv(
    const unsigned short* __restrict__ A,
    const unsigned short* __restrict__ Bt,
    const int* __restrict__ tok,
    unsigned short* __restrict__ Qo,
    unsigned short* __restrict__ Ko,
    unsigned short* __restrict__ Vt) {
  __shared__ unsigned short As[2][128 * 32];
  __shared__ unsigned short Bs[2][128 * 32];
  const int tid = threadIdx.x;
  const int bid = blockIdx.x;          // 768 blocks
  const int xcd = bid & 7;
  const int loc = bid >> 3;            // 0..95
  const int m0 = (loc / 3) * 128;
  const int n0 = (xcd * 3 + loc % 3) * 128;
  const int w = tid >> 6, lane = tid & 63;
  const int ln = lane & 15, quad = lane >> 4;
  const int wm = (w >> 1) * 64, wn = (w & 1) * 64;

  const int rr = lane >> 2;
  const int gsw = ((lane & 3) ^ ((rr ^ (rr >> 2)) & 3)) * 8;
  const int sr = (ln ^ (ln >> 2)) & 3;   // read-side swizzle

  const f32x4 zero = {0.f, 0.f, 0.f, 0.f};
  f32x4 acc[4][4];
#pragma unroll
  for (int i = 0; i < 4; ++i)
#pragma unroll
    for (int j = 0; j < 4; ++j) acc[i][j] = zero;

#define QKV_STAGE(kb, p)                                                              \
  do {                                                                                \
    int col = (kb) * 32 + gsw;                                                        \
    gl2lds16(A  + (size_t)(m0 + w * 32 + rr) * KDIM + col,      &As[p][(w * 32) * 32]);      \
    gl2lds16(A  + (size_t)(m0 + w * 32 + 16 + rr) * KDIM + col, &As[p][(w * 32 + 16) * 32]); \
    gl2lds16(Bt + (size_t)(n0 + w * 32 + rr) * KDIM + col,      &Bs[p][(w * 32) * 32]);      \
    gl2lds16(Bt + (size_t)(n0 + w * 32 + 16 + rr) * KDIM + col, &Bs[p][(w * 32 + 16) * 32]); \
  } while (0)

  QKV_STAGE(0, 0);
  for (int kb = 0; kb < 32; ++kb) {
    const int p = kb & 1;
    __syncthreads();
    if (kb < 31) QKV_STAGE(kb + 1, p ^ 1);
    s16x8 af[4], bfr[4];
#pragma unroll
    for (int i = 0; i < 4; ++i)
      af[i] = *(const s16x8*)(&As[p][(wm + i * 16 + ln) * 32 + ((quad ^ sr) * 8)]);
#pragma unroll
    for (int j = 0; j < 4; ++j)
      bfr[j] = *(const s16x8*)(&Bs[p][(wn + j * 16 + ln) * 32 + ((quad ^ sr) * 8)]);
#pragma unroll
    for (int i = 0; i < 4; ++i)
#pragma unroll
      for (int j = 0; j < 4; ++j)
        acc[i][j] = __builtin_amdgcn_mfma_f32_16x16x32_bf16(af[i], bfr[j], acc[i][j], 0, 0, 0);
  }
#undef QKV_STAGE

  __syncthreads();                      // all waves done reading As/Bs (epilogue reuses As)
  const bool isV = (n0 >= 2048);        // block-uniform (tiles fully Q, K, or V)
  if (!isV) {
    // Q/K: RoPE in regs, LDS transpose (16s x 64d per i-chunk), 128B stores.
    const float qs = (n0 + wn < 1024) ? QSCALE : 1.0f;
    const int gnb = n0 + wn;            // 64-aligned: one full head per wave
    const int h = (gnb & 1023) >> 6;    // uniform per wave
    unsigned short* dst = (gnb < 1024) ? Qo : Ko;
    unsigned short* T = &As[0][0] + w * 1088;   // per-wave 16 x 68 scratch
    float invj[4];
#pragma unroll
    for (int j = 0; j < 4; ++j)
      invj[j] = __expf(-0.2878231366f * (float)((j * 16 + ln) >> 1));
#pragma unroll
    for (int i = 0; i < 4; ++i) {
      const int mb = m0 + wm + i * 16;  // 16-row chunk, same b for all rows
      const int b = mb >> 11;
      const int sb = mb & 2047;
#pragma unroll
      for (int j = 0; j < 4; ++j) {
        const int dd = j * 16 + ln;
#pragma unroll
        for (int r = 0; r < 4; ++r) {
          float val = acc[i][j][r];
          float part = __shfl_xor(val, 1, 64);
          int s = sb + quad * 4 + r;
          float ang = (float)s * invj[j];   // positions are arange
          float sn, cs;
          __sincosf(ang, &sn, &cs);
          float x0 = (dd & 1) ? part : val;
          float x1 = (dd & 1) ? val : part;
          float y = (dd & 1) ? (x0 * sn + x1 * cs) : (x0 * cs - x1 * sn);
          T[(quad * 4 + r) * 68 + dd] = f2b(y * qs);
        }
      }
      __builtin_amdgcn_wave_barrier();    // DS in-order per wave
      const size_t obase = ((size_t)(b * 16 + h) * 2048 + sb) * 64;
#pragma unroll
      for (int ss = 0; ss < 16; ++ss)
        dst[obase + (size_t)ss * 64 + lane] = T[ss * 68 + lane];
      __builtin_amdgcn_wave_barrier();    // reads done before next i overwrite
    }
  } else {
    // V: transpose 16d x 64s tiles via LDS scratch (reuse As), coalesced stores
    unsigned short* T = &As[0][0] + w * 1120; // per-wave 16 x 64, stride 70
    const int b = m0 >> 11;
    const int hrow = ((n0 - 2048) + wn) >> 6; // head (uniform per wave)
    const int s0 = (m0 & 2047) + wm;
    const size_t vbase = (size_t)(b * 16 + hrow) * 64;
#pragma unroll
    for (int j = 0; j < 4; ++j) {
#pragma unroll
      for (int i = 0; i < 4; ++i)
#pragma unroll
        for (int r = 0; r < 4; ++r)
          T[ln * 70 + i * 16 + quad * 4 + r] = f2b(acc[i][j][r]);
      __builtin_amdgcn_wave_barrier();        // DS in-order per wave
#pragma unroll
      for (int dd = 0; dd < 16; ++dd)
        Vt[(vbase + j * 16 + dd) * 2048 + s0 + lane] = T[dd * 70 + lane];
      __builtin_amdgcn_wave_barrier();        // reads done before next j overwrite
    }
  }
}

// ---------------------------------------------------------------- split-K flash attention (dbuf LDS staging)
// R7: exact R4 revert — the 42.7us known-good. R5 (va hoist) spilled; R6
// (8-wave blocks) lost to barrier skew: causal skip leaves low-qb waves
// idling at 8-wave __syncthreads. 4-wave/128-row/KVBLK-64 is locally optimal.
// Pt XOR-swizzled (LDS 40960), launch_bounds (256,3) — (256,4) spills (R3).
__global__ __launch_bounds__(256, 3) void attn_partial(
    const unsigned short* __restrict__ Q,
    const unsigned short* __restrict__ K,
    const unsigned short* __restrict__ Vt,
    unsigned short* __restrict__ Opart,
    float2* __restrict__ ML) {
  __shared__ unsigned short Ks[2][64 * 64];
  __shared__ unsigned short Vs[2][64 * 64];
  __shared__ unsigned short Pt[4][16 * 64];   // per-wave 2048 B, XOR-swizzled

  const int bid = blockIdx.x;          // 1280 blocks
  const int xcd = bid & 7;
  const int loc = bid >> 3;            // 0..159
  const int bh = xcd * 4 + (loc & 3);
  const int widx = loc >> 2;           // 0..39, heavy-first
  int c, qh;
  if (widx < 28) {
    if (widx < 13)      { c = 0; qh = 3 + widx; }
    else if (widx < 22) { c = 1; qh = 7 + (widx - 13); }
    else if (widx < 27) { c = 2; qh = 11 + (widx - 22); }
    else                { c = 3; qh = 15; }
  } else {
    int s = widx - 28;
    int wt = s >> 2;
    c = s & 3;
    qh = 4 * c + 2 - wt;
  }
  const int kbeg = c * 512;
  const int khi = min(kbeg + 512, qh * 128 + 128);
  const int nit = (khi - kbeg) >> 6;   // 1..8, uniform per block

  const int tid = threadIdx.x;
  const int w = tid >> 6, lane = tid & 63;
  const int ln = lane & 15, quad = lane >> 4;
  const int qb = qh * 128 + w * 32;

  const unsigned short* Qb = Q + (size_t)bh * 2048 * 64;
  const unsigned short* Kb = K + (size_t)bh * 2048 * 64;
  const unsigned short* Vb = Vt + (size_t)bh * 64 * 2048;

  const int srow = w * 16 + (lane >> 3);
  const int sg = (lane & 7) ^ (srow & 7);

#define ATTN_STAGE(k0, p)                                                            \
  do {                                                                               \
    gl2lds16(Kb + (size_t)((k0) + srow) * 64 + sg * 8,       &Ks[p][(w * 16) * 64]);      \
    gl2lds16(Kb + (size_t)((k0) + srow + 8) * 64 + sg * 8,   &Ks[p][(w * 16 + 8) * 64]);  \
    gl2lds16(Vb + (size_t)srow * 2048 + (k0) + sg * 8,       &Vs[p][(w * 16) * 64]);      \
    gl2lds16(Vb + (size_t)(srow + 8) * 2048 + (k0) + sg * 8, &Vs[p][(w * 16 + 8) * 64]);  \
  } while (0)

  s16x8 bq[2][2];
#pragma unroll
  for (int u = 0; u < 2; ++u)
#pragma unroll
    for (int hh = 0; hh < 2; ++hh)
      bq[u][hh] = *(const s16x8*)(&Qb[(size_t)(qb + u * 16 + ln) * 64 + hh * 32 + quad * 8]);

  const f32x4 zero = {0.f, 0.f, 0.f, 0.f};
  f32x4 o[2][4];
#pragma unroll
  for (int u = 0; u < 2; ++u)
#pragma unroll
    for (int j = 0; j < 4; ++j) o[u][j] = zero;
  float m_i[2] = {-3e38f, -3e38f};
  float l_i[2] = {0.f, 0.f};

  const int rdsw = ((ln & 7) * 8);
  unsigned char* ptb = (unsigned char*)&Pt[w][0];
  const int pswz = (ln & 7) << 4;      // XOR swizzle for stride-64 rows

  ATTN_STAGE(kbeg, 0);
  for (int it = 0; it < nit; ++it) {
    const int p = it & 1;
    const int k0 = kbeg + it * 64;
    __syncthreads();                         // buf p staged; buf p^1 free
    if (it + 1 < nit) ATTN_STAGE(k0 + 64, p ^ 1);

    if (k0 <= qb + 31) {                     // wave-tile not fully above diagonal
      s16x8 ka[4][2];
#pragma unroll
      for (int t = 0; t < 4; ++t)
#pragma unroll
        for (int hh = 0; hh < 2; ++hh)
          ka[t][hh] = *(const s16x8*)(&Ks[p][(t * 16 + ln) * 64 + (((hh * 4 + quad) * 8) ^ rdsw)]);

#pragma unroll
      for (int u = 0; u < 2; ++u) {
        const int qlo = qb + u * 16;
        if (k0 > qlo + 15) continue;         // this u-half fully masked
        f32x4 st[4];
#pragma unroll
        for (int t = 0; t < 4; ++t) {
          f32x4 s = __builtin_amdgcn_mfma_f32_16x16x32_bf16(ka[t][0], bq[u][0], zero, 0, 0, 0);
          st[t] = __builtin_amdgcn_mfma_f32_16x16x32_bf16(ka[t][1], bq[u][1], s, 0, 0, 0);
        }
        float lm = -3e38f;
        if (k0 + 63 > qlo) {
          // diagonal tile: apply causal mask
          const int q = qlo + ln;
#pragma unroll
          for (int t = 0; t < 4; ++t)
#pragma unroll
            for (int r = 0; r < 4; ++r) {
              int kk = k0 + t * 16 + quad * 4 + r;
              float v = st[t][r];
              v = (kk > q) ? -3e38f : v;
              st[t][r] = v;
              lm = fmaxf(lm, v);
            }
        } else {
          // interior tile: no masking needed
#pragma unroll
          for (int t = 0; t < 4; ++t)
#pragma unroll
            for (int r = 0; r < 4; ++r) lm = fmaxf(lm, st[t][r]);
        }
        lm = fmaxf(lm, __shfl_xor(lm, 16, 64));
        lm = fmaxf(lm, __shfl_xor(lm, 32, 64));

        float rs = 0.f;
        if (__all(lm <= m_i[u])) {
          // running max unchanged: al == 1 exactly, skip rescale
          const float mn = m_i[u];
#pragma unroll
          for (int t = 0; t < 4; ++t)
#pragma unroll
            for (int r = 0; r < 4; ++r) {
              float pv = fexp2(st[t][r] - mn);
              st[t][r] = pv;
              rs += pv;
            }
          rs += __shfl_xor(rs, 16, 64);
          rs += __shfl_xor(rs, 32, 64);
          l_i[u] += rs;
        } else {
          const float mn = fmaxf(m_i[u], lm);
          const float al = fexp2(m_i[u] - mn);
#pragma unroll
          for (int t = 0; t < 4; ++t)
#pragma unroll
            for (int r = 0; r < 4; ++r) {
              float pv = fexp2(st[t][r] - mn);
              st[t][r] = pv;
              rs += pv;
            }
          rs += __shfl_xor(rs, 16, 64);
          rs += __shfl_xor(rs, 32, 64);
          m_i[u] = mn;
          l_i[u] = l_i[u] * al + rs;
#pragma unroll
          for (int j = 0; j < 4; ++j) o[u][j] *= al;
        }

#pragma unroll
        for (int t = 0; t < 4; ++t) {
          uint2 pv;
          pv.x = cvtpk(st[t][0], st[t][1]);
          pv.y = cvtpk(st[t][2], st[t][3]);
          *(uint2*)(ptb + ln * 128 + ((t * 32 + quad * 8) ^ pswz)) = pv;
        }
        __builtin_amdgcn_wave_barrier();
#pragma unroll
        for (int hh = 0; hh < 2; ++hh) {
          s16x8 pb = *(const s16x8*)(ptb + ln * 128 + ((hh * 64 + quad * 16) ^ pswz));
#pragma unroll
          for (int j = 0; j < 4; ++j) {
            s16x8 va = *(const s16x8*)(&Vs[p][(j * 16 + ln) * 64 + (((hh * 4 + quad) * 8) ^ rdsw)]);
            o[u][j] = __builtin_amdgcn_mfma_f32_16x16x32_bf16(va, pb, o[u][j], 0, 0, 0);
          }
        }
        __builtin_amdgcn_wave_barrier();
      }
    }
  }
#undef ATTN_STAGE

#pragma unroll
  for (int u = 0; u < 2; ++u) {
    int s = qb + u * 16 + ln;
    size_t row = ((size_t)bh * 4 + c) * 2048 + s;
    if (quad == 0) ML[row] = make_float2(m_i[u], l_i[u]);
    size_t base = row * 64;
#pragma unroll
    for (int j = 0; j < 4; ++j) {
      uint2 o4;
      o4.x = cvtpk(o[u][j][0], o[u][j][1]);
      o4.y = cvtpk(o[u][j][2], o[u][j][3]);
      *(uint2*)(&Opart[base + j * 16 + quad * 4]) = o4;
    }
  }
}

// ---------------------------------------------------------------- merge partials -> Ab
__global__ __launch_bounds__(256) void attn_merge(
    const unsigned short* __restrict__ Opart,
    const float2* __restrict__ ML,
    unsigned short* __restrict__ Ao) {
  int idx = blockIdx.x * 256 + threadIdx.x;
  int d0 = (idx & 7) * 8;
  int q  = (idx >> 3) & 2047;
  int bh = idx >> 14;
  int nc = (q >> 9) + 1;

  float m_c[4], l_c[4];
  float M = -3e38f;
  for (int c = 0; c < nc; ++c) {
    float2 ml = ML[((size_t)bh * 4 + c) * 2048 + q];
    m_c[c] = ml.x; l_c[c] = ml.y;
    M = fmaxf(M, ml.x);
  }
  float acc[8] = {0, 0, 0, 0, 0, 0, 0, 0};
  float L = 0.f;
  for (int c = 0; c < nc; ++c) {
    float wc = fexp2(m_c[c] - M);      // log2-domain running max
    L += wc * l_c[c];
    const ushort4* p = (const ushort4*)(Opart + (((size_t)bh * 4 + c) * 2048 + q) * 64 + d0);
    ushort4 a = p[0], bvec = p[1];
    acc[0] += wc * b2f(a.x); acc[1] += wc * b2f(a.y);
    acc[2] += wc * b2f(a.z); acc[3] += wc * b2f(a.w);
    acc[4] += wc * b2f(bvec.x); acc[5] += wc * b2f(bvec.y);
    acc[6] += wc * b2f(bvec.z); acc[7] += wc * b2f(bvec.w);
  }
  float invL = 1.0f / L;
  int b = bh >> 4, h = bh & 15;
  unsigned short* dst = Ao + ((size_t)b * 2048 + q) * 1024 + h * 64 + d0;
  uint2 o0, o1;
  o0.x = cvtpk(acc[0] * invL, acc[1] * invL);
  o0.y = cvtpk(acc[2] * invL, acc[3] * invL);
  o1.x = cvtpk(acc[4] * invL, acc[5] * invL);
  o1.y = cvtpk(acc[6] * invL, acc[7] * invL);
  ((uint2*)dst)[0] = o0;
  ((uint2*)dst)[1] = o1;
}

// ---------------------------------------------------------------- output projection GEMM
// R7: double-buffered BK=32 (exact port of gemm_qkv's proven main loop).
// Old version was single-buffered with 2 barriers/K-step at grid 256 =
// 1 block/CU — zero TLP, staging latency fully exposed 16x per block.
__global__ __launch_bounds__(256, 3) void gemm_out(
    const unsigned short* __restrict__ A,
    const unsigned short* __restrict__ Bt,
    float* __restrict__ out) {
  __shared__ unsigned short As[2][128 * 32];
  __shared__ unsigned short Bs[2][128 * 32];
  const int tid = threadIdx.x;
  const int bid = blockIdx.x;          // 256 blocks
  const int m0 = (bid >> 3) * 128;
  const int n0 = (bid & 7) * 128;
  const int w = tid >> 6, lane = tid & 63;
  const int ln = lane & 15, quad = lane >> 4;
  const int wm = (w >> 1) * 64, wn = (w & 1) * 64;

  const int rr = lane >> 2;
  const int gsw = ((lane & 3) ^ ((rr ^ (rr >> 2)) & 3)) * 8;
  const int sr = (ln ^ (ln >> 2)) & 3;   // read-side swizzle

  const f32x4 zero = {0.f, 0.f, 0.f, 0.f};
  f32x4 acc[4][4];
#pragma unroll
  for (int i = 0; i < 4; ++i)
#pragma unroll
    for (int j = 0; j < 4; ++j) acc[i][j] = zero;

#define OUT_STAGE(kb, p)                                                              \
  do {                                                                                \
    int col = (kb) * 32 + gsw;                                                        \
    gl2lds16(A  + (size_t)(m0 + w * 32 + rr) * KDIM + col,      &As[p][(w * 32) * 32]);      \
    gl2lds16(A  + (size_t)(m0 + w * 32 + 16 + rr) * KDIM + col, &As[p][(w * 32 + 16) * 32]); \
    gl2lds16(Bt + (size_t)(n0 + w * 32 + rr) * KDIM + col,      &Bs[p][(w * 32) * 32]);      \
    gl2lds16(Bt + (size_t)(n0 + w * 32 + 16 + rr) * KDIM + col, &Bs[p][(w * 32 + 16) * 32]); \
  } while (0)

  OUT_STAGE(0, 0);
  for (int kb = 0; kb < 32; ++kb) {
    const int p = kb & 1;
    __syncthreads();
    if (kb < 31) OUT_STAGE(kb + 1, p ^ 1);
    s16x8 af[4], bfr[4];
#pragma unroll
    for (int i = 0; i < 4; ++i)
      af[i] = *(const s16x8*)(&As[p][(wm + i * 16 + ln) * 32 + ((quad ^ sr) * 8)]);
#pragma unroll
    for (int j = 0; j < 4; ++j)
      bfr[j] = *(const s16x8*)(&Bs[p][(wn + j * 16 + ln) * 32 + ((quad ^ sr) * 8)]);
#pragma unroll
    for (int i = 0; i < 4; ++i)
#pragma unroll
      for (int j = 0; j < 4; ++j)
        acc[i][j] = __builtin_amdgcn_mfma_f32_16x16x32_bf16(af[i], bfr[j], acc[i][j], 0, 0, 0);
  }
#undef OUT_STAGE

#pragma unroll
  for (int i = 0; i < 4; ++i) {
    int gmb = m0 + wm + i * 16 + quad * 4;
#pragma unroll
    for (int j = 0; j < 4; ++j) {
      int gn = n0 + wn + j * 16 + ln;
#pragma unroll
      for (int r = 0; r < 4; ++r)
        out[(size_t)(gmb + r) * 1024 + gn] = acc[i][j][r];
    }
  }
}

// ---------------------------------------------------------------- launch
extern "C" void kernel_launch(void* const* d_in, const int* in_sizes, int n_in,
                              void* d_out, int out_size, void* d_ws, size_t ws_size,
                              hipStream_t stream) {
  const float* x  = (const float*)d_in[0];
  const float* Wq = (const float*)d_in[1];
  const float* Wk = (const float*)d_in[2];
  const float* Wv = (const float*)d_in[3];
  const float* Wo = (const float*)d_in[4];
  const int* tok  = (const int*)d_in[5];
  float* out = (float*)d_out;

  char* ws = (char*)d_ws;
  unsigned short* xb    = (unsigned short*)(ws);                  // 8 MB
  unsigned short* Wcat  = (unsigned short*)(ws + (8ull  << 20));  // 6 MB
  unsigned short* Wob   = (unsigned short*)(ws + (14ull << 20));  // 2 MB
  unsigned short* Qb    = (unsigned short*)(ws + (16ull << 20));  // 8 MB
  unsigned short* Kb    = (unsigned short*)(ws + (24ull << 20));  // 8 MB
  unsigned short* Vtb   = (unsigned short*)(ws + (32ull << 20));  // 8 MB
  unsigned short* Ab    = (unsigned short*)(ws + (40ull << 20));  // 8 MB
  unsigned short* Opart = (unsigned short*)(ws + (48ull << 20));  // 32 MB
  float2*         ML    = (float2*)        (ws + (80ull << 20));  // 2 MB

  cast_all<<<dim3(8192), dim3(256), 0, stream>>>(x, Wq, Wk, Wv, Wo, xb);
  gemm_qkv<<<dim3(768), dim3(256), 0, stream>>>(xb, Wcat, tok, Qb, Kb, Vtb);
  attn_partial<<<dim3(1280), dim3(256), 0, stream>>>(Qb, Kb, Vtb, Opart, ML);
  attn_merge<<<dim3(2048), dim3(256), 0, stream>>>(Opart, ML, Ab);
  gemm_out<<<dim3(256), dim3(256), 0, stream>>>(Ab, Wob, out);
}

// Round 8
// 183.582 us; speedup vs baseline: 1.4683x; 1.0173x over previous
//
#include <hip/hip_runtime.h>
#include <hip/hip_bf16.h>

typedef __attribute__((ext_vector_type(8))) short s16x8;
typedef __attribute__((ext_vector_type(4))) float f32x4;

__device__ __forceinline__ unsigned short f2b(float x) {
  unsigned int u = __float_as_uint(x);
  u = (u + 0x7fffu + ((u >> 16) & 1u)) >> 16;
  return (unsigned short)u;
}

__device__ __forceinline__ float b2f(unsigned short u) {
  return __uint_as_float((unsigned int)u << 16);
}

// packed f32x2 -> bf16x2 (RNE), lo = a, hi = b
__device__ __forceinline__ unsigned int cvtpk(float a, float b) {
  unsigned int r;
  asm("v_cvt_pk_bf16_f32 %0, %1, %2" : "=v"(r) : "v"(a), "v"(b));
  return r;
}

#if __has_builtin(__builtin_amdgcn_exp2f)
__device__ __forceinline__ float fexp2(float x) { return __builtin_amdgcn_exp2f(x); }
#else
__device__ __forceinline__ float fexp2(float x) { return exp2f(x); }
#endif

// async 16B/lane global->LDS (lane i lands at lds + i*16)
__device__ __forceinline__ void gl2lds16(const unsigned short* g, unsigned short* lds) {
  __builtin_amdgcn_global_load_lds(
      (const __attribute__((address_space(1))) unsigned int*)g,
      (__attribute__((address_space(3))) unsigned int*)lds, 16, 0, 0);
}

#define QSCALE 0.18033688011f  /* 0.125 * log2(e): scores land in log2 domain */

// ---------------------------------------------------------------- fused cast fp32 -> bf16
__global__ __launch_bounds__(256) void cast_all(
    const float* __restrict__ x,  const float* __restrict__ Wq,
    const float* __restrict__ Wk, const float* __restrict__ Wv,
    const float* __restrict__ Wo, unsigned short* __restrict__ dst) {
  int i = blockIdx.x * 256 + threadIdx.x;
  const float* src;
  int off;
  if (i < 1048576) { src = x; off = i; }
  else {
    int j = i - 1048576;
    int seg = j >> 18;
    off = j & 262143;
    src = (seg == 0) ? Wq : (seg == 1) ? Wk : (seg == 2) ? Wv : Wo;
  }
  const float4 v = ((const float4*)src)[off];
  uint2 o;
  o.x = cvtpk(v.x, v.y);
  o.y = cvtpk(v.z, v.w);
  ((uint2*)dst)[i] = o;
}

#define KDIM 1024

// ---------------------------------------------------------------- QKV GEMM + fused RoPE
// Bs-in-LDS dbuf BK=32 (R6 note: B-direct-to-reg regressed — B loads share
// vmcnt with global_load_lds, draining the staging pipeline; keep LDS path).
// Epilogue: RoPE in regs (native __sincosf; do NOT table: R1), per-wave LDS
// transpose for full 128B stores (R2). Q pre-scaled 0.125*log2e.
__global__ __launch_bounds__(256, 4) void gemm_qkv(
    const unsigned short* __restrict__ A,
    const unsigned short* __restrict__ Bt,
    const int* __restrict__ tok,
    unsigned short* __restrict__ Qo,
    unsigned short* __restrict__ Ko,
    unsigned short* __restrict__ Vt) {
  __shared__ unsigned short As[2][128 * 32];
  __shared__ unsigned short Bs[2][128 * 32];
  const int tid = threadIdx.x;
  const int bid = blockIdx.x;          // 768 blocks
  const int xcd = bid & 7;
  const int loc = bid >> 3;            // 0..95
  const int m0 = (loc / 3) * 128;
  const int n0 = (xcd * 3 + loc % 3) * 128;
  const int w = tid >> 6, lane = tid & 63;
  const int ln = lane & 15, quad = lane >> 4;
  const int wm = (w >> 1) * 64, wn = (w & 1) * 64;

  const int rr = lane >> 2;
  const int gsw = ((lane & 3) ^ ((rr ^ (rr >> 2)) & 3)) * 8;
  const int sr = (ln ^ (ln >> 2)) & 3;   // read-side swizzle

  const f32x4 zero = {0.f, 0.f, 0.f, 0.f};
  f32x4 acc[4][4];
#pragma unroll
  for (int i = 0; i < 4; ++i)
#pragma unroll
    for (int j = 0; j < 4; ++j) acc[i][j] = zero;

#define QKV_STAGE(kb, p)                                                              \
  do {                                                                                \
    int col = (kb) * 32 + gsw;                                                        \
    gl2lds16(A  + (size_t)(m0 + w * 32 + rr) * KDIM + col,      &As[p][(w * 32) * 32]);      \
    gl2lds16(A  + (size_t)(m0 + w * 32 + 16 + rr) * KDIM + col, &As[p][(w * 32 + 16) * 32]); \
    gl2lds16(Bt + (size_t)(n0 + w * 32 + rr) * KDIM + col,      &Bs[p][(w * 32) * 32]);      \
    gl2lds16(Bt + (size_t)(n0 + w * 32 + 16 + rr) * KDIM + col, &Bs[p][(w * 32 + 16) * 32]); \
  } while (0)

  QKV_STAGE(0, 0);
  for (int kb = 0; kb < 32; ++kb) {
    const int p = kb & 1;
    __syncthreads();
    if (kb < 31) QKV_STAGE(kb + 1, p ^ 1);
    s16x8 af[4], bfr[4];
#pragma unroll
    for (int i = 0; i < 4; ++i)
      af[i] = *(const s16x8*)(&As[p][(wm + i * 16 + ln) * 32 + ((quad ^ sr) * 8)]);
#pragma unroll
    for (int j = 0; j < 4; ++j)
      bfr[j] = *(const s16x8*)(&Bs[p][(wn + j * 16 + ln) * 32 + ((quad ^ sr) * 8)]);
#pragma unroll
    for (int i = 0; i < 4; ++i)
#pragma unroll
      for (int j = 0; j < 4; ++j)
        acc[i][j] = __builtin_amdgcn_mfma_f32_16x16x32_bf16(af[i], bfr[j], acc[i][j], 0, 0, 0);
  }
#undef QKV_STAGE

  __syncthreads();                      // all waves done reading As/Bs (epilogue reuses As)
  const bool isV = (n0 >= 2048);        // block-uniform (tiles fully Q, K, or V)
  if (!isV) {
    // Q/K: RoPE in regs, LDS transpose (16s x 64d per i-chunk), 128B stores.
    const float qs = (n0 + wn < 1024) ? QSCALE : 1.0f;
    const int gnb = n0 + wn;            // 64-aligned: one full head per wave
    const int h = (gnb & 1023) >> 6;    // uniform per wave
    unsigned short* dst = (gnb < 1024) ? Qo : Ko;
    unsigned short* T = &As[0][0] + w * 1088;   // per-wave 16 x 68 scratch
    float invj[4];
#pragma unroll
    for (int j = 0; j < 4; ++j)
      invj[j] = __expf(-0.2878231366f * (float)((j * 16 + ln) >> 1));
#pragma unroll
    for (int i = 0; i < 4; ++i) {
      const int mb = m0 + wm + i * 16;  // 16-row chunk, same b for all rows
      const int b = mb >> 11;
      const int sb = mb & 2047;
#pragma unroll
      for (int j = 0; j < 4; ++j) {
        const int dd = j * 16 + ln;
#pragma unroll
        for (int r = 0; r < 4; ++r) {
          float val = acc[i][j][r];
          float part = __shfl_xor(val, 1, 64);
          int s = sb + quad * 4 + r;
          float ang = (float)s * invj[j];   // positions are arange
          float sn, cs;
          __sincosf(ang, &sn, &cs);
          float x0 = (dd & 1) ? part : val;
          float x1 = (dd & 1) ? val : part;
          float y = (dd & 1) ? (x0 * sn + x1 * cs) : (x0 * cs - x1 * sn);
          T[(quad * 4 + r) * 68 + dd] = f2b(y * qs);
        }
      }
      __builtin_amdgcn_wave_barrier();    // DS in-order per wave
      const size_t obase = ((size_t)(b * 16 + h) * 2048 + sb) * 64;
#pragma unroll
      for (int ss = 0; ss < 16; ++ss)
        dst[obase + (size_t)ss * 64 + lane] = T[ss * 68 + lane];
      __builtin_amdgcn_wave_barrier();    // reads done before next i overwrite
    }
  } else {
    // V: transpose 16d x 64s tiles via LDS scratch (reuse As), coalesced stores
    unsigned short* T = &As[0][0] + w * 1120; // per-wave 16 x 64, stride 70
    const int b = m0 >> 11;
    const int hrow = ((n0 - 2048) + wn) >> 6; // head (uniform per wave)
    const int s0 = (m0 & 2047) + wm;
    const size_t vbase = (size_t)(b * 16 + hrow) * 64;
#pragma unroll
    for (int j = 0; j < 4; ++j) {
#pragma unroll
      for (int i = 0; i < 4; ++i)
#pragma unroll
        for (int r = 0; r < 4; ++r)
          T[ln * 70 + i * 16 + quad * 4 + r] = f2b(acc[i][j][r]);
      __builtin_amdgcn_wave_barrier();        // DS in-order per wave
#pragma unroll
      for (int dd = 0; dd < 16; ++dd)
        Vt[(vbase + j * 16 + dd) * 2048 + s0 + lane] = T[dd * 70 + lane];
      __builtin_amdgcn_wave_barrier();        // reads done before next j overwrite
    }
  }
}

// ---------------------------------------------------------------- split-K flash attention (dbuf LDS staging)
// R8 = R4 + deferred-l ONLY (the safe component of R5): al is row-uniform, so
// l_i legally stays a per-lane partial; the 2x shfl_xor rs-reduce per u-tile
// (2 ds_swizzle ~100cyc on the serial chain) moves to one butterfly after the
// k-loop. Register-neutral. R5's va-hoist (spilled) NOT re-applied.
// Pt XOR-swizzled (LDS 40960), launch_bounds (256,3) — (256,4) spills (R3).
// 4-wave/128-row/KVBLK-64 is locally optimal (R6 8-wave lost to barrier skew).
__global__ __launch_bounds__(256, 3) void attn_partial(
    const unsigned short* __restrict__ Q,
    const unsigned short* __restrict__ K,
    const unsigned short* __restrict__ Vt,
    unsigned short* __restrict__ Opart,
    float2* __restrict__ ML) {
  __shared__ unsigned short Ks[2][64 * 64];
  __shared__ unsigned short Vs[2][64 * 64];
  __shared__ unsigned short Pt[4][16 * 64];   // per-wave 2048 B, XOR-swizzled

  const int bid = blockIdx.x;          // 1280 blocks
  const int xcd = bid & 7;
  const int loc = bid >> 3;            // 0..159
  const int bh = xcd * 4 + (loc & 3);
  const int widx = loc >> 2;           // 0..39, heavy-first
  int c, qh;
  if (widx < 28) {
    if (widx < 13)      { c = 0; qh = 3 + widx; }
    else if (widx < 22) { c = 1; qh = 7 + (widx - 13); }
    else if (widx < 27) { c = 2; qh = 11 + (widx - 22); }
    else                { c = 3; qh = 15; }
  } else {
    int s = widx - 28;
    int wt = s >> 2;
    c = s & 3;
    qh = 4 * c + 2 - wt;
  }
  const int kbeg = c * 512;
  const int khi = min(kbeg + 512, qh * 128 + 128);
  const int nit = (khi - kbeg) >> 6;   // 1..8, uniform per block

  const int tid = threadIdx.x;
  const int w = tid >> 6, lane = tid & 63;
  const int ln = lane & 15, quad = lane >> 4;
  const int qb = qh * 128 + w * 32;

  const unsigned short* Qb = Q + (size_t)bh * 2048 * 64;
  const unsigned short* Kb = K + (size_t)bh * 2048 * 64;
  const unsigned short* Vb = Vt + (size_t)bh * 64 * 2048;

  const int srow = w * 16 + (lane >> 3);
  const int sg = (lane & 7) ^ (srow & 7);

#define ATTN_STAGE(k0, p)                                                            \
  do {                                                                               \
    gl2lds16(Kb + (size_t)((k0) + srow) * 64 + sg * 8,       &Ks[p][(w * 16) * 64]);      \
    gl2lds16(Kb + (size_t)((k0) + srow + 8) * 64 + sg * 8,   &Ks[p][(w * 16 + 8) * 64]);  \
    gl2lds16(Vb + (size_t)srow * 2048 + (k0) + sg * 8,       &Vs[p][(w * 16) * 64]);      \
    gl2lds16(Vb + (size_t)(srow + 8) * 2048 + (k0) + sg * 8, &Vs[p][(w * 16 + 8) * 64]);  \
  } while (0)

  s16x8 bq[2][2];
#pragma unroll
  for (int u = 0; u < 2; ++u)
#pragma unroll
    for (int hh = 0; hh < 2; ++hh)
      bq[u][hh] = *(const s16x8*)(&Qb[(size_t)(qb + u * 16 + ln) * 64 + hh * 32 + quad * 8]);

  const f32x4 zero = {0.f, 0.f, 0.f, 0.f};
  f32x4 o[2][4];
#pragma unroll
  for (int u = 0; u < 2; ++u)
#pragma unroll
    for (int j = 0; j < 4; ++j) o[u][j] = zero;
  float m_i[2] = {-3e38f, -3e38f};
  float l_i[2] = {0.f, 0.f};           // per-lane partials until final butterfly

  const int rdsw = ((ln & 7) * 8);
  unsigned char* ptb = (unsigned char*)&Pt[w][0];
  const int pswz = (ln & 7) << 4;      // XOR swizzle for stride-64 rows

  ATTN_STAGE(kbeg, 0);
  for (int it = 0; it < nit; ++it) {
    const int p = it & 1;
    const int k0 = kbeg + it * 64;
    __syncthreads();                         // buf p staged; buf p^1 free
    if (it + 1 < nit) ATTN_STAGE(k0 + 64, p ^ 1);

    if (k0 <= qb + 31) {                     // wave-tile not fully above diagonal
      s16x8 ka[4][2];
#pragma unroll
      for (int t = 0; t < 4; ++t)
#pragma unroll
        for (int hh = 0; hh < 2; ++hh)
          ka[t][hh] = *(const s16x8*)(&Ks[p][(t * 16 + ln) * 64 + (((hh * 4 + quad) * 8) ^ rdsw)]);

#pragma unroll
      for (int u = 0; u < 2; ++u) {
        const int qlo = qb + u * 16;
        if (k0 > qlo + 15) continue;         // this u-half fully masked
        f32x4 st[4];
#pragma unroll
        for (int t = 0; t < 4; ++t) {
          f32x4 s = __builtin_amdgcn_mfma_f32_16x16x32_bf16(ka[t][0], bq[u][0], zero, 0, 0, 0);
          st[t] = __builtin_amdgcn_mfma_f32_16x16x32_bf16(ka[t][1], bq[u][1], s, 0, 0, 0);
        }
        float lm = -3e38f;
        if (k0 + 63 > qlo) {
          // diagonal tile: apply causal mask
          const int q = qlo + ln;
#pragma unroll
          for (int t = 0; t < 4; ++t)
#pragma unroll
            for (int r = 0; r < 4; ++r) {
              int kk = k0 + t * 16 + quad * 4 + r;
              float v = st[t][r];
              v = (kk > q) ? -3e38f : v;
              st[t][r] = v;
              lm = fmaxf(lm, v);
            }
        } else {
          // interior tile: no masking needed
#pragma unroll
          for (int t = 0; t < 4; ++t)
#pragma unroll
            for (int r = 0; r < 4; ++r) lm = fmaxf(lm, st[t][r]);
        }
        lm = fmaxf(lm, __shfl_xor(lm, 16, 64));
        lm = fmaxf(lm, __shfl_xor(lm, 32, 64));

        float rs = 0.f;
        if (__all(lm <= m_i[u])) {
          // running max unchanged: al == 1 exactly, skip rescale
          const float mn = m_i[u];
#pragma unroll
          for (int t = 0; t < 4; ++t)
#pragma unroll
            for (int r = 0; r < 4; ++r) {
              float pv = fexp2(st[t][r] - mn);
              st[t][r] = pv;
              rs += pv;
            }
          l_i[u] += rs;                      // per-lane partial
        } else {
          const float mn = fmaxf(m_i[u], lm);
          const float al = fexp2(m_i[u] - mn);  // row-uniform (lm reduced over quads)
#pragma unroll
          for (int t = 0; t < 4; ++t)
#pragma unroll
            for (int r = 0; r < 4; ++r) {
              float pv = fexp2(st[t][r] - mn);
              st[t][r] = pv;
              rs += pv;
            }
          m_i[u] = mn;
          l_i[u] = l_i[u] * al + rs;         // per-lane partial
#pragma unroll
          for (int j = 0; j < 4; ++j) o[u][j] *= al;
        }

#pragma unroll
        for (int t = 0; t < 4; ++t) {
          uint2 pv;
          pv.x = cvtpk(st[t][0], st[t][1]);
          pv.y = cvtpk(st[t][2], st[t][3]);
          *(uint2*)(ptb + ln * 128 + ((t * 32 + quad * 8) ^ pswz)) = pv;
        }
        __builtin_amdgcn_wave_barrier();
#pragma unroll
        for (int hh = 0; hh < 2; ++hh) {
          s16x8 pb = *(const s16x8*)(ptb + ln * 128 + ((hh * 64 + quad * 16) ^ pswz));
#pragma unroll
          for (int j = 0; j < 4; ++j) {
            s16x8 va = *(const s16x8*)(&Vs[p][(j * 16 + ln) * 64 + (((hh * 4 + quad) * 8) ^ rdsw)]);
            o[u][j] = __builtin_amdgcn_mfma_f32_16x16x32_bf16(va, pb, o[u][j], 0, 0, 0);
          }
        }
        __builtin_amdgcn_wave_barrier();
      }
    }
  }
#undef ATTN_STAGE

  // final cross-lane reduce of the deferred l partials (once, off the hot chain)
#pragma unroll
  for (int u = 0; u < 2; ++u) {
    l_i[u] += __shfl_xor(l_i[u], 16, 64);
    l_i[u] += __shfl_xor(l_i[u], 32, 64);
  }

#pragma unroll
  for (int u = 0; u < 2; ++u) {
    int s = qb + u * 16 + ln;
    size_t row = ((size_t)bh * 4 + c) * 2048 + s;
    if (quad == 0) ML[row] = make_float2(m_i[u], l_i[u]);
    size_t base = row * 64;
#pragma unroll
    for (int j = 0; j < 4; ++j) {
      uint2 o4;
      o4.x = cvtpk(o[u][j][0], o[u][j][1]);
      o4.y = cvtpk(o[u][j][2], o[u][j][3]);
      *(uint2*)(&Opart[base + j * 16 + quad * 4]) = o4;
    }
  }
}

// ---------------------------------------------------------------- merge partials -> Ab
__global__ __launch_bounds__(256) void attn_merge(
    const unsigned short* __restrict__ Opart,
    const float2* __restrict__ ML,
    unsigned short* __restrict__ Ao) {
  int idx = blockIdx.x * 256 + threadIdx.x;
  int d0 = (idx & 7) * 8;
  int q  = (idx >> 3) & 2047;
  int bh = idx >> 14;
  int nc = (q >> 9) + 1;

  float m_c[4], l_c[4];
  float M = -3e38f;
  for (int c = 0; c < nc; ++c) {
    float2 ml = ML[((size_t)bh * 4 + c) * 2048 + q];
    m_c[c] = ml.x; l_c[c] = ml.y;
    M = fmaxf(M, ml.x);
  }
  float acc[8] = {0, 0, 0, 0, 0, 0, 0, 0};
  float L = 0.f;
  for (int c = 0; c < nc; ++c) {
    float wc = fexp2(m_c[c] - M);      // log2-domain running max
    L += wc * l_c[c];
    const ushort4* p = (const ushort4*)(Opart + (((size_t)bh * 4 + c) * 2048 + q) * 64 + d0);
    ushort4 a = p[0], bvec = p[1];
    acc[0] += wc * b2f(a.x); acc[1] += wc * b2f(a.y);
    acc[2] += wc * b2f(a.z); acc[3] += wc * b2f(a.w);
    acc[4] += wc * b2f(bvec.x); acc[5] += wc * b2f(bvec.y);
    acc[6] += wc * b2f(bvec.z); acc[7] += wc * b2f(bvec.w);
  }
  float invL = 1.0f / L;
  int b = bh >> 4, h = bh & 15;
  unsigned short* dst = Ao + ((size_t)b * 2048 + q) * 1024 + h * 64 + d0;
  uint2 o0, o1;
  o0.x = cvtpk(acc[0] * invL, acc[1] * invL);
  o0.y = cvtpk(acc[2] * invL, acc[3] * invL);
  o1.x = cvtpk(acc[4] * invL, acc[5] * invL);
  o1.y = cvtpk(acc[6] * invL, acc[7] * invL);
  ((uint2*)dst)[0] = o0;
  ((uint2*)dst)[1] = o1;
}

// ---------------------------------------------------------------- output projection GEMM
// single-buffered BK=64, (256,3) residency cap. R7's dbuf BK=32 port measured
// ~2.5us WORSE (more barrier crossings, each draining vmcnt, at 1 block/CU) —
// keep this version.
__global__ __launch_bounds__(256, 3) void gemm_out(
    const unsigned short* __restrict__ A,
    const unsigned short* __restrict__ Bt,
    float* __restrict__ out) {
  __shared__ unsigned short As[128 * 64];
  __shared__ unsigned short Bs[128 * 64];
  const int tid = threadIdx.x;
  const int bid = blockIdx.x;          // 256 blocks
  const int m0 = (bid >> 3) * 128;
  const int n0 = (bid & 7) * 128;
  const int w = tid >> 6, lane = tid & 63;
  const int ln = lane & 15, quad = lane >> 4;
  const int wm = (w >> 1) * 64, wn = (w & 1) * 64;

  const int srow = w * 32 + (lane >> 3);
  const int sg = (lane & 7) ^ (lane >> 3);
  const int rs = ln & 7;

  const f32x4 zero = {0.f, 0.f, 0.f, 0.f};
  f32x4 acc[4][4];
#pragma unroll
  for (int i = 0; i < 4; ++i)
#pragma unroll
    for (int j = 0; j < 4; ++j) acc[i][j] = zero;

  for (int kb = 0; kb < KDIM / 64; ++kb) {
    __syncthreads();
#pragma unroll
    for (int t = 0; t < 4; ++t) {
      gl2lds16(A  + (size_t)(m0 + srow + t * 8) * KDIM + kb * 64 + sg * 8, &As[(w * 32 + t * 8) * 64]);
      gl2lds16(Bt + (size_t)(n0 + srow + t * 8) * KDIM + kb * 64 + sg * 8, &Bs[(w * 32 + t * 8) * 64]);
    }
    __syncthreads();
#pragma unroll
    for (int ks = 0; ks < 2; ++ks) {
      s16x8 af[4], bfr[4];
#pragma unroll
      for (int i = 0; i < 4; ++i)
        af[i] = *(const s16x8*)(&As[(wm + i * 16 + ln) * 64 + (((ks * 4 + quad) ^ rs) * 8)]);
#pragma unroll
      for (int j = 0; j < 4; ++j)
        bfr[j] = *(const s16x8*)(&Bs[(wn + j * 16 + ln) * 64 + (((ks * 4 + quad) ^ rs) * 8)]);
#pragma unroll
      for (int i = 0; i < 4; ++i)
#pragma unroll
        for (int j = 0; j < 4; ++j)
          acc[i][j] = __builtin_amdgcn_mfma_f32_16x16x32_bf16(af[i], bfr[j], acc[i][j], 0, 0, 0);
    }
  }
#pragma unroll
  for (int i = 0; i < 4; ++i) {
    int gmb = m0 + wm + i * 16 + quad * 4;
#pragma unroll
    for (int j = 0; j < 4; ++j) {
      int gn = n0 + wn + j * 16 + ln;
#pragma unroll
      for (int r = 0; r < 4; ++r)
        out[(size_t)(gmb + r) * 1024 + gn] = acc[i][j][r];
    }
  }
}

// ---------------------------------------------------------------- launch
extern "C" void kernel_launch(void* const* d_in, const int* in_sizes, int n_in,
                              void* d_out, int out_size, void* d_ws, size_t ws_size,
                              hipStream_t stream) {
  const float* x  = (const float*)d_in[0];
  const float* Wq = (const float*)d_in[1];
  const float* Wk = (const float*)d_in[2];
  const float* Wv = (const float*)d_in[3];
  const float* Wo = (const float*)d_in[4];
  const int* tok  = (const int*)d_in[5];
  float* out = (float*)d_out;

  char* ws = (char*)d_ws;
  unsigned short* xb    = (unsigned short*)(ws);                  // 8 MB
  unsigned short* Wcat  = (unsigned short*)(ws + (8ull  << 20));  // 6 MB
  unsigned short* Wob   = (unsigned short*)(ws + (14ull << 20));  // 2 MB
  unsigned short* Qb    = (unsigned short*)(ws + (16ull << 20));  // 8 MB
  unsigned short* Kb    = (unsigned short*)(ws + (24ull << 20));  // 8 MB
  unsigned short* Vtb   = (unsigned short*)(ws + (32ull << 20));  // 8 MB
  unsigned short* Ab    = (unsigned short*)(ws + (40ull << 20));  // 8 MB
  unsigned short* Opart = (unsigned short*)(ws + (48ull << 20));  // 32 MB
  float2*         ML    = (float2*)        (ws + (80ull << 20));  // 2 MB

  cast_all<<<dim3(8192), dim3(256), 0, stream>>>(x, Wq, Wk, Wv, Wo, xb);
  gemm_qkv<<<dim3(768), dim3(256), 0, stream>>>(xb, Wcat, tok, Qb, Kb, Vtb);
  attn_partial<<<dim3(1280), dim3(256), 0, stream>>>(Qb, Kb, Vtb, Opart, ML);
  attn_merge<<<dim3(2048), dim3(256), 0, stream>>>(Opart, ML, Ab);
  gemm_out<<<dim3(256), dim3(256), 0, stream>>>(Ab, Wob, out);
}